// Round 12
// baseline (47579.230 us; speedup 1.0000x reference)
//
#include <hip/hip_runtime.h>

#define TT 512
#define BB 256
#define DD 128
#define HH 512
#define KA 1152
#define KB 1024
#define NKA 36
#define NKB 32

// ---- ws byte-offset layout ----
#define OFF_WPA  0ull
#define SZ_WPA   (128ull*NKA*2ull*512ull*2ull)     // [colblk][kb][spl][lane][8] bf16
#define OFF_WPB  (OFF_WPA + SZ_WPA)
#define SZ_WPB   (128ull*NKB*2ull*512ull*2ull)
#define OFF_WZFA (OFF_WPB + SZ_WPB)                // [kb][lane][8] u16 (col0=hi,col1=lo)
#define SZ_WZFA  (36ull*512ull*2ull)
#define OFF_WZFB (OFF_WZFA + SZ_WZFA)
#define SZ_WZFB  (32ull*512ull*2ull)
#define OFF_BP1  (OFF_WZFB + SZ_WZFB)              // f32[2048] permuted bias l1
#define OFF_BP2  (OFF_BP1 + 8192ull)
#define OFF_BZ   (OFF_BP2 + 8192ull)               // bz1, bz2
#define OFF_CNT  (OFF_BZ + 256ull)                 // 16 group counters, 256B apart
#define OFF_A1   (OFF_CNT + 4096ull)               // 2 bufs x [2spl][64kg][256row][8] u16
#define OFF_A2   (OFF_A1 + 2ull*524288ull)         // 1 buf
#define OFF_B1   (OFF_A2 + 524288ull)              // 2 bufs
#define OFF_B2   (OFF_B1 + 2ull*524288ull)         // 1 buf
#define OFF_END  (OFF_B2 + 524288ull)

#define PLSTR 131072   // u16 stride between split planes within an act buffer

typedef __bf16 bf16x8 __attribute__((ext_vector_type(8)));
typedef float  f32x4  __attribute__((ext_vector_type(4)));
typedef unsigned short u16;

__device__ __forceinline__ u16 bf_bits(__bf16 h) {
  union { __bf16 b; u16 u; } cv; cv.b = h; return cv.u;
}
__device__ __forceinline__ float sigmoidf_(float v) { return 1.f / (1.f + __expf(-v)); }

// uncached (device-coherent) u16 store: sc0 sc1 -> write-through to coherence point
__device__ __forceinline__ void st_uc(u16* p, u16 v) {
  unsigned vv = v;
  asm volatile("global_store_short %0, %1, off sc0 sc1" :: "v"(p), "v"(vv) : "memory");
}
__device__ __forceinline__ void split_st_uc(u16* hi, u16* lo, float v) {
  __bf16 h = (__bf16)v;
  __bf16 l = (__bf16)(v - (float)h);
  st_uc(hi, bf_bits(h));
  st_uc(lo, bf_bits(l));
}
// explicit drain of ALL outstanding VMEM ops of this wave (inline-asm stores are
// invisible to the compiler's waitcnt scoreboard)
__device__ __forceinline__ void drain_vmem() {
  asm volatile("s_waitcnt vmcnt(0)" ::: "memory");
}

// global->LDS DMA, 16B/lane, cpol aux = SC0|NT|SC1 = 19 (device-coherent read; R7-proven)
__device__ __forceinline__ void gload_lds16_uc(const void* g, void* l) {
  __builtin_amdgcn_global_load_lds((const __attribute__((address_space(1))) unsigned int*)g,
                                   (__attribute__((address_space(3))) unsigned int*)l, 16, 0, 19);
}

// stage one 16KB chunk (kb = c*8..c*8+7, both splits) into buf[2][8][64][8]
__device__ __forceinline__ void stage_chunk(const u16* first, const u16* second, int c,
                                            int nw, int kgp, int grow, u16* buf) {
  for (int j = 0; j < 4; ++j) {
    int idx = nw*4 + j;          // 0..15
    int spl = idx >> 3;          // 0..1
    int kbl = idx & 7;           // 0..7
    int kb  = c*8 + kbl;         // 0..31
    const u16* base = (kb < 16) ? first : second;
    int kq = kb & 15;
    const u16* src = base + spl*PLSTR + ((size_t)((kq*4 + kgp)*256 + grow))*8;
    gload_lds16_uc(src, buf + ((size_t)(spl*8 + kbl)*64)*8);
  }
}

// ---------------- pack kernels (identical layouts to R5/R7) ----------------
__global__ void pack_w(const float* __restrict__ U11_1, const float* __restrict__ U21_1,
                       const float* __restrict__ W01_1, const float* __restrict__ U11_2,
                       const float* __restrict__ W01_2, u16* __restrict__ wp) {
  unsigned i = blockIdx.x * 256u + threadIdx.x;
  const unsigned NWA = 128u * NKA * 2u * 512u;
  const unsigned NWB = 128u * NKB * 2u * 512u;
  if (i >= NWA + NWB) return;
  float w; unsigned s;
  if (i < NWA) {
    unsigned lane = (i >> 3) & 63u, e = i & 7u; s = (i >> 9) & 1u;
    unsigned blk = i >> 10, kb = blk % NKA, colblk = blk / NKA;
    unsigned c = colblk * 16u + (lane & 15u);
    unsigned n = (c & 3u) * 512u + (c >> 2);
    unsigned k = kb * 32u + (lane >> 4) * 8u + e;
    w = (k < 512u)  ? U11_1[n * 512u + k]
      : (k < 1024u) ? U21_1[n * 512u + (k - 512u)]
                    : W01_1[n * 128u + (k - 1024u)];
  } else {
    unsigned j = i - NWA;
    unsigned lane = (j >> 3) & 63u, e = j & 7u; s = (j >> 9) & 1u;
    unsigned blk = j >> 10, kb = blk % NKB, colblk = blk / NKB;
    unsigned c = colblk * 16u + (lane & 15u);
    unsigned n = (c & 3u) * 512u + (c >> 2);
    unsigned k = kb * 32u + (lane >> 4) * 8u + e;
    w = (k < 512u) ? U11_2[n * 512u + k] : W01_2[n * 512u + (k - 512u)];
  }
  __bf16 hi = (__bf16)w;
  __bf16 v = s ? (__bf16)(w - (float)hi) : hi;
  wp[i] = bf_bits(v);
}

__global__ void pack_wz(const float* __restrict__ U11_1, const float* __restrict__ U21_1,
                        const float* __restrict__ W01_1, const float* __restrict__ U11_2,
                        const float* __restrict__ W01_2,
                        u16* __restrict__ wzfa, u16* __restrict__ wzfb) {
  unsigned i = blockIdx.x * 256u + threadIdx.x;
  const unsigned NZA = 36u * 512u, NZB = 32u * 512u;
  if (i >= NZA + NZB) return;
  const bool isA = i < NZA;
  unsigned j = isA ? i : i - NZA;
  unsigned e = j & 7u, lane = (j >> 3) & 63u, kb = j >> 9;
  unsigned col = lane & 15u;
  unsigned k = kb * 32u + (lane >> 4) * 8u + e;
  float wz;
  if (isA) {
    wz = (k < 512u)  ? U11_1[2048u*512u + k]
       : (k < 1024u) ? U21_1[2048u*512u + (k-512u)]
                     : W01_1[2048u*128u + (k-1024u)];
  } else {
    wz = (k < 512u) ? U11_2[2048u*512u + k] : W01_2[2048u*512u + (k-512u)];
  }
  u16 out = 0;
  if (col == 0u) out = bf_bits((__bf16)wz);
  else if (col == 1u) { __bf16 h = (__bf16)wz; out = bf_bits((__bf16)(wz - (float)h)); }
  (isA ? wzfa : wzfb)[j] = out;
}

__global__ void pack_bias(const float* __restrict__ b1, const float* __restrict__ b2,
                          float* __restrict__ bp1, float* __restrict__ bp2,
                          float* __restrict__ bz) {
  unsigned i = blockIdx.x * 256u + threadIdx.x;
  if (i < 2048u) bp1[i] = b1[(i & 3u)*512u + (i >> 2)];
  else if (i < 4096u) { unsigned c = i - 2048u; bp2[c] = b2[(c & 3u)*512u + (c >> 2)]; }
  else if (i == 4096u) bz[0] = b1[2048];
  else if (i == 4097u) bz[1] = b2[2048];
}

// zero act buffers + counters
__global__ void init_zero(char* __restrict__ wsb) {
  size_t i = (size_t)blockIdx.x * 256u + threadIdx.x;
  size_t n = (OFF_END - OFF_CNT) / 4u;
  if (i < n) ((unsigned*)(wsb + OFF_CNT))[i] = 0u;
}

// ---------------- main persistent kernel ----------------
// 512 WGs x 256 threads (4 waves), REGULAR launch (no grid.sync anywhere; custom
// counter barriers only need co-residency, which resource arithmetic guarantees:
// 37 KB LDS + 88 VGPR -> 2 WGs/CU with 2x LDS headroom; all 512 dispatch at once).
// WG = 16 rows (mg 0..15) x 16 units (ntg 0..31). Co-resident CU pair differs in
// mg -> independent barrier domains: one WG computes while the other waits (TLP).
// bid = [mg:4][q:2][xcd:3]: XCD x hosts ntg {4x..4x+3} -> 2.2 MB L2-resident weights.
// Acts staged in 4 chunked double-buffered 16KB pieces (m97 pattern), always
// in-phase (fenced by the preceding group barrier). Group barrier (16 groups x 32
// arrivals): counter + tid0 relaxed agent RMW/poll; release = drain_vmem +
// __syncthreads (R7-proven).
__global__ __launch_bounds__(256, 2) void hmlstm_kernel(const float* __restrict__ x,
                                                        char* __restrict__ wsb,
                                                        float* __restrict__ y) {
  const int tid  = threadIdx.x;
  const int lane = tid & 63;
  const int nw   = __builtin_amdgcn_readfirstlane(tid >> 6);   // 0..3
  const int bid  = blockIdx.x;
  const int xcd  = bid & 7;
  const int q    = (bid >> 3) & 3;
  const int mg   = bid >> 5;                 // 0..15
  const int ntg  = xcd * 4 + q;              // 0..31 (16 units each)
  const int b0   = mg * 16;

  const u16* wpA  = (const u16*)(wsb + OFF_WPA);
  const u16* wpB  = (const u16*)(wsb + OFF_WPB);
  const u16* wzfA = (const u16*)(wsb + OFF_WZFA);
  const u16* wzfB = (const u16*)(wsb + OFF_WZFB);
  const float* bp1 = (const float*)(wsb + OFF_BP1);
  const float* bp2 = (const float*)(wsb + OFF_BP2);
  const float bz1 = ((const float*)(wsb + OFF_BZ))[0];
  const float bz2 = ((const float*)(wsb + OFF_BZ))[1];
  unsigned* cnt = (unsigned*)(wsb + OFF_CNT) + mg * 64;   // own 256B line
  u16* A1b[2] = { (u16*)(wsb + OFF_A1), (u16*)(wsb + OFF_A1 + 524288ull) };
  u16* A2b    =   (u16*)(wsb + OFF_A2);
  u16* B1b[2] = { (u16*)(wsb + OFF_B1), (u16*)(wsb + OFF_B1 + 524288ull) };
  u16* B2b    =   (u16*)(wsb + OFF_B2);

  __shared__ u16 stg[2][2][8][64][8];   // 2 chunk bufs x [spl][kb8][lane][8] = 32 KB
  __shared__ float ls_s[16][68];
  __shared__ float zp[3][16];

  const int kgp   = lane >> 4;    // k-slot 0..3
  const int row16 = lane & 15;    // frag row 0..15
  const int er = tid >> 4, eu = tid & 15;   // epilogue (row, unit-in-WG)
  const int erow = b0 + er;
  const int ku = ntg * 16 + eu;             // global hidden-unit index 0..511
  const size_t pidx = ((size_t)(ku >> 3) * 256 + erow) * 8 + (ku & 7);

  const u16* wbA = wpA + (size_t)(ntg*4 + nw) * (NKA*1024u) + lane*8;
  const u16* wbB = wpB + (size_t)(ntg*4 + nw) * (NKB*1024u) + lane*8;
  const u16* wzA = wzfA + lane*8;
  const u16* wzB = wzfB + lane*8;

  // per-thread recurrent state (row er, unit eu fixed across steps)
  float c1r = 0.f, c2r = 0.f, h2r = 0.f;
  float z1p = 0.f, z2p = 0.f, z1c = 0.f;
  unsigned bar_tgt = 32u;
  int p = 0;

  const int grow = b0 + row16;   // staging source row for this lane

  for (int t = 0; t < TT; ++t) {
    // ======== PHASE A ========
    {
      const u16* first  = A1b[p];   // k 0..511  (fenced by barrier#2 of t-1; zeros at t=0)
      const u16* second = A2b;      // k 512..1023
      f32x4 acc0={0,0,0,0}, acc1={0,0,0,0}, acc2={0,0,0,0};
      f32x4 az={0,0,0,0};

      stage_chunk(first, second, 0, nw, kgp, grow, &stg[0][0][0][0][0]);
      // x fragments on the fly (cached f32 reads, static input)
      bf16x8 xah[4], xal[4];
      {
        const float* xp = x + ((size_t)grow * TT + t) * DD + kgp*8;
        for (int k4 = 0; k4 < 4; ++k4) {
          float4 v0 = *(const float4*)(xp + k4*32);
          float4 v1 = *(const float4*)(xp + k4*32 + 4);
          float vv[8] = {v0.x,v0.y,v0.z,v0.w,v1.x,v1.y,v1.z,v1.w};
          for (int e = 0; e < 8; ++e) {
            __bf16 h = (__bf16)vv[e];
            xah[k4][e] = h;
            xal[k4][e] = (__bf16)(vv[e] - (float)h);
          }
        }
      }
      __syncthreads();   // chunk 0 staged

      for (int c = 0; c < 4; ++c) {
        const u16* cur = &stg[c & 1][0][0][0][0];
        if (c < 3) stage_chunk(first, second, c + 1, nw, kgp, grow, &stg[(c + 1) & 1][0][0][0][0]);
        #pragma unroll
        for (int kbl = 0; kbl < 8; ++kbl) {
          int kb = c*8 + kbl;
          const u16* sa = cur + ((size_t)kbl*64 + lane)*8;
          bf16x8 ah = *(const bf16x8*)sa;
          bf16x8 al = *(const bf16x8*)(sa + 4096);
          bf16x8 wh = *(const bf16x8*)(wbA + kb*1024);
          bf16x8 wl = *(const bf16x8*)(wbA + kb*1024 + 512);
          acc0 = __builtin_amdgcn_mfma_f32_16x16x32_bf16(ah, wh, acc0, 0, 0, 0);
          acc1 = __builtin_amdgcn_mfma_f32_16x16x32_bf16(ah, wl, acc1, 0, 0, 0);
          acc2 = __builtin_amdgcn_mfma_f32_16x16x32_bf16(al, wh, acc2, 0, 0, 0);
          if (nw == 0) { bf16x8 zf = *(const bf16x8*)(wzA + kb*512);
                         az = __builtin_amdgcn_mfma_f32_16x16x32_bf16(ah, zf, az, 0, 0, 0); }
          if (nw == 1) { bf16x8 zf = *(const bf16x8*)(wzA + kb*512);
                         az = __builtin_amdgcn_mfma_f32_16x16x32_bf16(al, zf, az, 0, 0, 0); }
        }
        __syncthreads();   // chunk c+1 landed; buf c free for reuse
      }
      // x tail (kb 32..35, from registers)
      for (int k4 = 0; k4 < 4; ++k4) {
        int kb = 32 + k4;
        bf16x8 ah = xah[k4], al = xal[k4];
        bf16x8 wh = *(const bf16x8*)(wbA + kb*1024);
        bf16x8 wl = *(const bf16x8*)(wbA + kb*1024 + 512);
        acc0 = __builtin_amdgcn_mfma_f32_16x16x32_bf16(ah, wh, acc0, 0, 0, 0);
        acc1 = __builtin_amdgcn_mfma_f32_16x16x32_bf16(ah, wl, acc1, 0, 0, 0);
        acc2 = __builtin_amdgcn_mfma_f32_16x16x32_bf16(al, wh, acc2, 0, 0, 0);
        if (nw == 0) { bf16x8 zf = *(const bf16x8*)(wzA + kb*512);
                       az = __builtin_amdgcn_mfma_f32_16x16x32_bf16(ah, zf, az, 0, 0, 0); }
        if (nw == 1) { bf16x8 zf = *(const bf16x8*)(wzA + kb*512);
                       az = __builtin_amdgcn_mfma_f32_16x16x32_bf16(al, zf, az, 0, 0, 0); }
      }
      f32x4 accs = acc0 + acc1; accs = accs + acc2;
      int cc = nw*16 + (lane & 15);
      int r0 = (lane >> 4) * 4;
      ls_s[r0+0][cc] = accs[0]; ls_s[r0+1][cc] = accs[1];
      ls_s[r0+2][cc] = accs[2]; ls_s[r0+3][cc] = accs[3];
      if (nw == 0 && (lane&15) == 0) {
        for (int j2 = 0; j2 < 4; ++j2) zp[0][r0+j2] = az[j2];
      }
      if (nw == 0 && (lane&15) == 1) {
        for (int j2 = 0; j2 < 4; ++j2) zp[1][r0+j2] = az[j2];
      }
      if (nw == 1 && (lane&15) == 0) {
        for (int j2 = 0; j2 < 4; ++j2) zp[2][r0+j2] = az[j2];
      }
    }
    __syncthreads();
    {
      // epilogue layer 1 (zb==1); znew computed inline per-thread
      float zs = zp[0][er] + zp[1][er] + zp[2][er] + bz1;
      float zn = fminf(fmaxf((zs + 1.f)*0.5f, 0.f), 1.f);
      float4 sv = *(const float4*)&ls_s[er][4*eu];
      float4 bb = *(const float4*)&bp1[ntg*64 + 4*eu];
      float f = sigmoidf_(sv.x + bb.x);
      float i = sigmoidf_(sv.y + bb.y);
      float o = sigmoidf_(sv.z + bb.z);
      float g = tanhf(sv.w + bb.w);
      float z = z1p;
      float ig = i * g;
      float cn = z * ig + (1.f - z) * fmaf(f, c1r, ig);
      float hn = o * tanhf(cn);
      c1r = cn;
      z1c = zn; z1p = zn;
      u16* a1w = A1b[p ^ 1];
      split_st_uc(a1w + pidx, a1w + PLSTR + pidx, (1.f - zn) * hn);   // A next step
      split_st_uc(B2b + pidx, B2b + PLSTR + pidx, zn * hn);           // B this step
    }
    drain_vmem();      // release: act stores at coherence point (asm stores untracked)
    __syncthreads();
    if (tid == 0) {
      __hip_atomic_fetch_add(cnt, 1u, __ATOMIC_RELAXED, __HIP_MEMORY_SCOPE_AGENT);
      while (__hip_atomic_load(cnt, __ATOMIC_RELAXED, __HIP_MEMORY_SCOPE_AGENT) < bar_tgt)
        __builtin_amdgcn_s_sleep(1);
    }
    bar_tgt += 32u;
    __builtin_amdgcn_s_barrier();

    // ======== PHASE B ========
    {
      const u16* first  = B1b[p];   // k 0..511  (phase B of t-1; zeros at t=0)
      const u16* second = B2b;      // k 512..1023 (phase A of step t, fenced by barrier#1)
      f32x4 acc0={0,0,0,0}, acc1={0,0,0,0}, acc2={0,0,0,0};
      f32x4 az={0,0,0,0};

      stage_chunk(first, second, 0, nw, kgp, grow, &stg[0][0][0][0][0]);
      __syncthreads();

      for (int c = 0; c < 4; ++c) {
        const u16* cur = &stg[c & 1][0][0][0][0];
        if (c < 3) stage_chunk(first, second, c + 1, nw, kgp, grow, &stg[(c + 1) & 1][0][0][0][0]);
        #pragma unroll
        for (int kbl = 0; kbl < 8; ++kbl) {
          int kb = c*8 + kbl;
          const u16* sa = cur + ((size_t)kbl*64 + lane)*8;
          bf16x8 ah = *(const bf16x8*)sa;
          bf16x8 al = *(const bf16x8*)(sa + 4096);
          bf16x8 wh = *(const bf16x8*)(wbB + kb*1024);
          bf16x8 wl = *(const bf16x8*)(wbB + kb*1024 + 512);
          acc0 = __builtin_amdgcn_mfma_f32_16x16x32_bf16(ah, wh, acc0, 0, 0, 0);
          acc1 = __builtin_amdgcn_mfma_f32_16x16x32_bf16(ah, wl, acc1, 0, 0, 0);
          acc2 = __builtin_amdgcn_mfma_f32_16x16x32_bf16(al, wh, acc2, 0, 0, 0);
          if (nw == 0) { bf16x8 zf = *(const bf16x8*)(wzB + kb*512);
                         az = __builtin_amdgcn_mfma_f32_16x16x32_bf16(ah, zf, az, 0, 0, 0); }
          if (nw == 1) { bf16x8 zf = *(const bf16x8*)(wzB + kb*512);
                         az = __builtin_amdgcn_mfma_f32_16x16x32_bf16(al, zf, az, 0, 0, 0); }
        }
        __syncthreads();
      }
      f32x4 accs = acc0 + acc1; accs = accs + acc2;
      int cc = nw*16 + (lane & 15);
      int r0 = (lane >> 4) * 4;
      ls_s[r0+0][cc] = accs[0]; ls_s[r0+1][cc] = accs[1];
      ls_s[r0+2][cc] = accs[2]; ls_s[r0+3][cc] = accs[3];
      if (nw == 0 && (lane&15) == 0) {
        for (int j2 = 0; j2 < 4; ++j2) zp[0][r0+j2] = az[j2];
      }
      if (nw == 0 && (lane&15) == 1) {
        for (int j2 = 0; j2 < 4; ++j2) zp[1][r0+j2] = az[j2];
      }
      if (nw == 1 && (lane&15) == 0) {
        for (int j2 = 0; j2 < 4; ++j2) zp[2][r0+j2] = az[j2];
      }
    }
    __syncthreads();
    {
      // epilogue layer 2: z = z2(t-1), zb = z1(t); znew inline
      float zs = zp[0][er] + zp[1][er] + zp[2][er] + bz2;
      float z2n_ = fminf(fmaxf((zs + 1.f)*0.5f, 0.f), 1.f);
      float4 sv = *(const float4*)&ls_s[er][4*eu];
      float4 bb = *(const float4*)&bp2[ntg*64 + 4*eu];
      float f = sigmoidf_(sv.x + bb.x);
      float i = sigmoidf_(sv.y + bb.y);
      float o = sigmoidf_(sv.z + bb.z);
      float g = tanhf(sv.w + bb.w);
      float z = z2p, zb = z1c;
      float ig = i * g;
      float cn = z*ig + (1.f-z)*(1.f-zb)*c2r + (1.f-z)*zb*fmaf(f, c2r, ig);
      float tc = tanhf(cn);
      float ot = o * tc;
      float hn = z*ot + (1.f-z)*(1.f-zb)*h2r + (1.f-z)*zb*ot;
      c2r = cn; h2r = hn;
      z2p = z2n_;
      y[((size_t)erow * TT + t) * HH + ku] = hn * z2n_;
      u16* b1w = B1b[p ^ 1];
      split_st_uc(b1w + pidx, b1w + PLSTR + pidx, (1.f - z2n_) * hn);  // B next step
      split_st_uc(A2b + pidx, A2b + PLSTR + pidx, z1c * hn);           // A next step
    }
    drain_vmem();
    __syncthreads();
    if (tid == 0) {
      __hip_atomic_fetch_add(cnt, 1u, __ATOMIC_RELAXED, __HIP_MEMORY_SCOPE_AGENT);
      while (__hip_atomic_load(cnt, __ATOMIC_RELAXED, __HIP_MEMORY_SCOPE_AGENT) < bar_tgt)
        __builtin_amdgcn_s_sleep(1);
    }
    bar_tgt += 32u;
    __builtin_amdgcn_s_barrier();

    p ^= 1;
  }
}

extern "C" void kernel_launch(void* const* d_in, const int* in_sizes, int n_in,
                              void* d_out, int out_size, void* d_ws, size_t ws_size,
                              hipStream_t stream) {
  const float* x     = (const float*)d_in[0];
  const float* U11_1 = (const float*)d_in[1];
  const float* U21_1 = (const float*)d_in[2];
  const float* W01_1 = (const float*)d_in[3];
  const float* b1    = (const float*)d_in[4];
  const float* U11_2 = (const float*)d_in[5];
  const float* W01_2 = (const float*)d_in[6];
  const float* b2    = (const float*)d_in[7];
  char*  wsb = (char*)d_ws;
  float* y   = (float*)d_out;
  (void)in_sizes; (void)n_in; (void)out_size; (void)ws_size;

  u16* wp    = (u16*)(wsb + OFF_WPA);
  u16* wzfa  = (u16*)(wsb + OFF_WZFA);
  u16* wzfb  = (u16*)(wsb + OFF_WZFB);
  float* bp1 = (float*)(wsb + OFF_BP1);
  float* bp2 = (float*)(wsb + OFF_BP2);
  float* bz  = (float*)(wsb + OFF_BZ);

  const unsigned NW = 128u*NKA*2u*512u + 128u*NKB*2u*512u;
  hipLaunchKernelGGL(pack_w, dim3((NW + 255u)/256u), dim3(256), 0, stream,
                     U11_1, U21_1, W01_1, U11_2, W01_2, wp);
  const unsigned NZ = 36u*512u + 32u*512u;
  hipLaunchKernelGGL(pack_wz, dim3((NZ + 255u)/256u), dim3(256), 0, stream,
                     U11_1, U21_1, W01_1, U11_2, W01_2, wzfa, wzfb);
  hipLaunchKernelGGL(pack_bias, dim3(17), dim3(256), 0, stream, b1, b2, bp1, bp2, bz);
  const unsigned n_zero_words = (unsigned)((OFF_END - OFF_CNT) / 4u);
  hipLaunchKernelGGL(init_zero, dim3((n_zero_words + 255u)/256u), dim3(256), 0, stream, wsb);

  // REGULAR launch: no grid.sync in the kernel (custom counter barriers only);
  // co-residency by resource arithmetic (2 WGs/CU with 2x LDS slack).
  hipLaunchKernelGGL(hmlstm_kernel, dim3(512), dim3(256), 0, stream, x, wsb, y);
}

// Round 13
// 40137.460 us; speedup vs baseline: 1.1854x; 1.1854x over previous
//
#include <hip/hip_runtime.h>

#define TT 512
#define BB 256
#define DD 128
#define HH 512
#define KA 1152
#define KB 1024
#define NKA 36
#define NKB 32

// ---- ws byte-offset layout ----
#define OFF_WPA  0ull
#define SZ_WPA   (128ull*NKA*2ull*512ull*2ull)     // [colblk][kb][spl][lane][8] bf16
#define OFF_WPB  (OFF_WPA + SZ_WPA)
#define SZ_WPB   (128ull*NKB*2ull*512ull*2ull)
#define OFF_WZFA (OFF_WPB + SZ_WPB)                // [kb][lane][8] u16 (col0=hi,col1=lo)
#define SZ_WZFA  (36ull*512ull*2ull)
#define OFF_WZFB (OFF_WZFA + SZ_WZFA)
#define SZ_WZFB  (32ull*512ull*2ull)
#define OFF_BP1  (OFF_WZFB + SZ_WZFB)              // f32[2048] permuted bias l1
#define OFF_BP2  (OFF_BP1 + 8192ull)
#define OFF_BZ   (OFF_BP2 + 8192ull)               // bz1, bz2
#define OFF_CNT  (OFF_BZ + 256ull)                 // 16 group counters, 256B apart
#define OFF_A1   (OFF_CNT + 4096ull)               // 2 bufs x [2spl][64kg][256row][8] u16
#define OFF_A2   (OFF_A1 + 2ull*524288ull)         // 1 buf
#define OFF_B1   (OFF_A2 + 524288ull)              // 2 bufs
#define OFF_B2   (OFF_B1 + 2ull*524288ull)         // 1 buf
#define OFF_END  (OFF_B2 + 524288ull)

#define PLSTR 131072   // u16 stride between split planes within an act buffer

typedef __bf16 bf16x8 __attribute__((ext_vector_type(8)));
typedef float  f32x4  __attribute__((ext_vector_type(4)));
typedef unsigned short u16;

__device__ __forceinline__ u16 bf_bits(__bf16 h) {
  union { __bf16 b; u16 u; } cv; cv.b = h; return cv.u;
}
__device__ __forceinline__ float sigmoidf_(float v) { return 1.f / (1.f + __expf(-v)); }

// uncached (device-coherent) u16 store: sc0 sc1 -> write-through to coherence point
__device__ __forceinline__ void st_uc(u16* p, u16 v) {
  unsigned vv = v;
  asm volatile("global_store_short %0, %1, off sc0 sc1" :: "v"(p), "v"(vv) : "memory");
}
__device__ __forceinline__ void split_st_uc(u16* hi, u16* lo, float v) {
  __bf16 h = (__bf16)v;
  __bf16 l = (__bf16)(v - (float)h);
  st_uc(hi, bf_bits(h));
  st_uc(lo, bf_bits(l));
}
// explicit drain of ALL outstanding VMEM ops of this wave (inline-asm stores are
// invisible to the compiler's waitcnt scoreboard -- __syncthreads alone is not enough)
__device__ __forceinline__ void drain_vmem() {
  asm volatile("s_waitcnt vmcnt(0)" ::: "memory");
}

// global->LDS DMA, 16B/lane, cpol aux = SC0|NT|SC1 = 19 (device-coherent read; R7-proven)
__device__ __forceinline__ void gload_lds16_uc(const void* g, void* l) {
  __builtin_amdgcn_global_load_lds((const __attribute__((address_space(1))) unsigned int*)g,
                                   (__attribute__((address_space(3))) unsigned int*)l, 16, 0, 19);
}

// ---------------- pack kernels (identical layouts to R5/R7) ----------------
__global__ void pack_w(const float* __restrict__ U11_1, const float* __restrict__ U21_1,
                       const float* __restrict__ W01_1, const float* __restrict__ U11_2,
                       const float* __restrict__ W01_2, u16* __restrict__ wp) {
  unsigned i = blockIdx.x * 256u + threadIdx.x;
  const unsigned NWA = 128u * NKA * 2u * 512u;
  const unsigned NWB = 128u * NKB * 2u * 512u;
  if (i >= NWA + NWB) return;
  float w; unsigned s;
  if (i < NWA) {
    unsigned lane = (i >> 3) & 63u, e = i & 7u; s = (i >> 9) & 1u;
    unsigned blk = i >> 10, kb = blk % NKA, colblk = blk / NKA;
    unsigned c = colblk * 16u + (lane & 15u);
    unsigned n = (c & 3u) * 512u + (c >> 2);
    unsigned k = kb * 32u + (lane >> 4) * 8u + e;
    w = (k < 512u)  ? U11_1[n * 512u + k]
      : (k < 1024u) ? U21_1[n * 512u + (k - 512u)]
                    : W01_1[n * 128u + (k - 1024u)];
  } else {
    unsigned j = i - NWA;
    unsigned lane = (j >> 3) & 63u, e = j & 7u; s = (j >> 9) & 1u;
    unsigned blk = j >> 10, kb = blk % NKB, colblk = blk / NKB;
    unsigned c = colblk * 16u + (lane & 15u);
    unsigned n = (c & 3u) * 512u + (c >> 2);
    unsigned k = kb * 32u + (lane >> 4) * 8u + e;
    w = (k < 512u) ? U11_2[n * 512u + k] : W01_2[n * 512u + (k - 512u)];
  }
  __bf16 hi = (__bf16)w;
  __bf16 v = s ? (__bf16)(w - (float)hi) : hi;
  wp[i] = bf_bits(v);
}

__global__ void pack_wz(const float* __restrict__ U11_1, const float* __restrict__ U21_1,
                        const float* __restrict__ W01_1, const float* __restrict__ U11_2,
                        const float* __restrict__ W01_2,
                        u16* __restrict__ wzfa, u16* __restrict__ wzfb) {
  unsigned i = blockIdx.x * 256u + threadIdx.x;
  const unsigned NZA = 36u * 512u, NZB = 32u * 512u;
  if (i >= NZA + NZB) return;
  const bool isA = i < NZA;
  unsigned j = isA ? i : i - NZA;
  unsigned e = j & 7u, lane = (j >> 3) & 63u, kb = j >> 9;
  unsigned col = lane & 15u;
  unsigned k = kb * 32u + (lane >> 4) * 8u + e;
  float wz;
  if (isA) {
    wz = (k < 512u)  ? U11_1[2048u*512u + k]
       : (k < 1024u) ? U21_1[2048u*512u + (k-512u)]
                     : W01_1[2048u*128u + (k-1024u)];
  } else {
    wz = (k < 512u) ? U11_2[2048u*512u + k] : W01_2[2048u*512u + (k-512u)];
  }
  u16 out = 0;
  if (col == 0u) out = bf_bits((__bf16)wz);
  else if (col == 1u) { __bf16 h = (__bf16)wz; out = bf_bits((__bf16)(wz - (float)h)); }
  (isA ? wzfa : wzfb)[j] = out;
}

__global__ void pack_bias(const float* __restrict__ b1, const float* __restrict__ b2,
                          float* __restrict__ bp1, float* __restrict__ bp2,
                          float* __restrict__ bz) {
  unsigned i = blockIdx.x * 256u + threadIdx.x;
  if (i < 2048u) bp1[i] = b1[(i & 3u)*512u + (i >> 2)];
  else if (i < 4096u) { unsigned c = i - 2048u; bp2[c] = b2[(c & 3u)*512u + (c >> 2)]; }
  else if (i == 4096u) bz[0] = b1[2048];
  else if (i == 4097u) bz[1] = b2[2048];
}

// zero act buffers + counters
__global__ void init_zero(char* __restrict__ wsb) {
  size_t i = (size_t)blockIdx.x * 256u + threadIdx.x;
  size_t n = (OFF_END - OFF_CNT) / 4u;
  if (i < n) ((unsigned*)(wsb + OFF_CNT))[i] = 0u;
}

// ---------------- main persistent kernel ----------------
// R7-proven structure: 256 WGs x 512 threads (cooperative), WG = 16 rows x 128 cols,
// XCD x hosts ntg {2x,2x+1} for all 16 mgs -> 2.2 MB L2-resident weights.
// 16 independent group barriers (counter + tid0 relaxed agent RMW/poll);
// release = drain_vmem + __syncthreads. This round adds ONLY scheduling changes:
// launch_bounds(512,1) (256-VGPR budget; LDS already caps at 1 WG/CU), unroll 8,
// and cross-barrier preload of the next phase's first 4 K-blocks of weights
// (constants -> no coherence dependency; latency hides under drain+barrier).
__global__ __launch_bounds__(512, 1) void hmlstm_kernel(const float* __restrict__ x,
                                                        char* __restrict__ wsb,
                                                        float* __restrict__ y) {
  const int tid  = threadIdx.x;
  const int lane = tid & 63;
  const int nw   = __builtin_amdgcn_readfirstlane(tid >> 6);
  const int bid  = blockIdx.x;
  const int ntg  = (bid & 7) * 2 + (bid >> 7);   // 0..15
  const int mg   = (bid >> 3) & 15;              // 0..15
  const int b0   = mg * 16;

  const u16* wpA  = (const u16*)(wsb + OFF_WPA);
  const u16* wpB  = (const u16*)(wsb + OFF_WPB);
  const u16* wzfA = (const u16*)(wsb + OFF_WZFA);
  const u16* wzfB = (const u16*)(wsb + OFF_WZFB);
  const float* bp1 = (const float*)(wsb + OFF_BP1);
  const float* bp2 = (const float*)(wsb + OFF_BP2);
  const float bz1 = ((const float*)(wsb + OFF_BZ))[0];
  const float bz2 = ((const float*)(wsb + OFF_BZ))[1];
  unsigned* cnt = (unsigned*)(wsb + OFF_CNT) + mg * 64;   // own 256B line
  u16* A1b[2] = { (u16*)(wsb + OFF_A1), (u16*)(wsb + OFF_A1 + 524288ull) };
  u16* A2b    =   (u16*)(wsb + OFF_A2);
  u16* B1b[2] = { (u16*)(wsb + OFF_B1), (u16*)(wsb + OFF_B1 + 524288ull) };
  u16* B2b    =   (u16*)(wsb + OFF_B2);

  __shared__ u16 stgA[2][2][16][64][8];   // 64 KB
  __shared__ u16 stgB[2][2][16][64][8];   // 64 KB
  __shared__ float ls_s[16][132];
  __shared__ float zp[3][16];

  const int kgp   = lane >> 4;    // k-slot 0..3
  const int row16 = lane & 15;    // frag row 0..15
  const int er = tid >> 5, eu = tid & 31;   // epilogue (row, unit-in-WG)
  const int erow = b0 + er;
  const int ku = ntg * 32 + eu;             // global hidden-unit index
  const size_t pidx = ((size_t)(ku >> 3) * 256 + erow) * 8 + (ku & 7);

  const u16* wbA = wpA + (size_t)(ntg*8 + nw) * (NKA*1024u) + lane*8;
  const u16* wbB = wpB + (size_t)(ntg*8 + nw) * (NKB*1024u) + lane*8;
  const u16* wzA = wzfA + lane*8;
  const u16* wzB = wzfB + lane*8;

  // per-thread recurrent state (row er, unit eu fixed across steps)
  float c1r = 0.f, c2r = 0.f, h2r = 0.f;
  float z1p = 0.f, z2p = 0.f, z1c = 0.f;
  unsigned bar_tgt = 16u;
  int p = 0;

  // cross-barrier weight preload registers (next phase's kb 0..3)
  bf16x8 preh[4], prel[4];
  #pragma unroll
  for (int kk = 0; kk < 4; ++kk) {       // prime for phase A of t=0
    preh[kk] = *(const bf16x8*)(wbA + kk*1024);
    prel[kk] = *(const bf16x8*)(wbA + kk*1024 + 512);
  }

  for (int t = 0; t < TT; ++t) {
    // ======== PHASE A ========
    if (t == 0) {   // no prior prefetch of A1[0]
      for (int j = 0; j < 4; ++j) {
        int i = nw*4 + j; int spl = i >> 4, kq = i & 15;
        const u16* src = A1b[0] + spl*PLSTR + ((size_t)((kq*4 + kgp)*256 + b0 + row16))*8;
        gload_lds16_uc(src, &stgA[0][spl][kq][0][0]);
      }
    }
    for (int j = 0; j < 4; ++j) {     // stage A2 half (fenced by barrier#2 of t-1)
      int i = nw*4 + j; int spl = i >> 4, kq = i & 15;
      const u16* src = A2b + spl*PLSTR + ((size_t)((kq*4 + kgp)*256 + b0 + row16))*8;
      gload_lds16_uc(src, &stgA[1][spl][kq][0][0]);
    }
    for (int j = 0; j < 4; ++j) {     // prefetch B1[p] (fenced by barrier#2 of t-1)
      int i = nw*4 + j; int spl = i >> 4, kq = i & 15;
      const u16* src = B1b[p] + spl*PLSTR + ((size_t)((kq*4 + kgp)*256 + b0 + row16))*8;
      gload_lds16_uc(src, &stgB[0][spl][kq][0][0]);
    }
    // x fragments on the fly (cached f32 reads, static input)
    bf16x8 xah[4], xal[4];
    {
      const float* xp = x + ((size_t)(b0 + row16) * TT + t) * DD + kgp*8;
      for (int k4 = 0; k4 < 4; ++k4) {
        float4 v0 = *(const float4*)(xp + k4*32);
        float4 v1 = *(const float4*)(xp + k4*32 + 4);
        float vv[8] = {v0.x,v0.y,v0.z,v0.w,v1.x,v1.y,v1.z,v1.w};
        for (int e = 0; e < 8; ++e) {
          __bf16 h = (__bf16)vv[e];
          xah[k4][e] = h;
          xal[k4][e] = (__bf16)(vv[e] - (float)h);
        }
      }
    }
    __syncthreads();   // drain staging DMAs + WG barrier

    {
      f32x4 acc0={0,0,0,0}, acc1={0,0,0,0}, acc2={0,0,0,0};
      f32x4 az={0,0,0,0};
      #pragma unroll
      for (int kb = 0; kb < 4; ++kb) {       // preloaded weights (cross-barrier)
        const u16* sa = &stgA[0][0][kb][lane][0];
        bf16x8 ah = *(const bf16x8*)sa;
        bf16x8 al = *(const bf16x8*)(sa + 8192);
        acc0 = __builtin_amdgcn_mfma_f32_16x16x32_bf16(ah, preh[kb], acc0, 0, 0, 0);
        acc1 = __builtin_amdgcn_mfma_f32_16x16x32_bf16(ah, prel[kb], acc1, 0, 0, 0);
        acc2 = __builtin_amdgcn_mfma_f32_16x16x32_bf16(al, preh[kb], acc2, 0, 0, 0);
        if (nw == 0) { bf16x8 zf = *(const bf16x8*)(wzA + kb*512);
                       az = __builtin_amdgcn_mfma_f32_16x16x32_bf16(ah, zf, az, 0, 0, 0); }
        if (nw == 1) { bf16x8 zf = *(const bf16x8*)(wzA + kb*512);
                       az = __builtin_amdgcn_mfma_f32_16x16x32_bf16(al, zf, az, 0, 0, 0); }
      }
      #pragma unroll 8
      for (int kb = 4; kb < 32; ++kb) {
        const u16* sa = &stgA[kb>>4][0][kb&15][lane][0];
        bf16x8 ah = *(const bf16x8*)sa;
        bf16x8 al = *(const bf16x8*)(sa + 8192);
        bf16x8 wh = *(const bf16x8*)(wbA + kb*1024);
        bf16x8 wl = *(const bf16x8*)(wbA + kb*1024 + 512);
        acc0 = __builtin_amdgcn_mfma_f32_16x16x32_bf16(ah, wh, acc0, 0, 0, 0);
        acc1 = __builtin_amdgcn_mfma_f32_16x16x32_bf16(ah, wl, acc1, 0, 0, 0);
        acc2 = __builtin_amdgcn_mfma_f32_16x16x32_bf16(al, wh, acc2, 0, 0, 0);
        if (nw == 0) { bf16x8 zf = *(const bf16x8*)(wzA + kb*512);
                       az = __builtin_amdgcn_mfma_f32_16x16x32_bf16(ah, zf, az, 0, 0, 0); }
        if (nw == 1) { bf16x8 zf = *(const bf16x8*)(wzA + kb*512);
                       az = __builtin_amdgcn_mfma_f32_16x16x32_bf16(al, zf, az, 0, 0, 0); }
      }
      for (int k4 = 0; k4 < 4; ++k4) {
        int kb = 32 + k4;
        bf16x8 ah = xah[k4], al = xal[k4];
        bf16x8 wh = *(const bf16x8*)(wbA + kb*1024);
        bf16x8 wl = *(const bf16x8*)(wbA + kb*1024 + 512);
        acc0 = __builtin_amdgcn_mfma_f32_16x16x32_bf16(ah, wh, acc0, 0, 0, 0);
        acc1 = __builtin_amdgcn_mfma_f32_16x16x32_bf16(ah, wl, acc1, 0, 0, 0);
        acc2 = __builtin_amdgcn_mfma_f32_16x16x32_bf16(al, wh, acc2, 0, 0, 0);
        if (nw == 0) { bf16x8 zf = *(const bf16x8*)(wzA + kb*512);
                       az = __builtin_amdgcn_mfma_f32_16x16x32_bf16(ah, zf, az, 0, 0, 0); }
        if (nw == 1) { bf16x8 zf = *(const bf16x8*)(wzA + kb*512);
                       az = __builtin_amdgcn_mfma_f32_16x16x32_bf16(al, zf, az, 0, 0, 0); }
      }
      f32x4 accs = acc0 + acc1; accs = accs + acc2;
      int cc = nw*16 + (lane & 15);
      int r0 = (lane >> 4) * 4;
      ls_s[r0+0][cc] = accs[0]; ls_s[r0+1][cc] = accs[1];
      ls_s[r0+2][cc] = accs[2]; ls_s[r0+3][cc] = accs[3];
      if (nw == 0 && (lane&15) == 0) {
        for (int j2 = 0; j2 < 4; ++j2) zp[0][r0+j2] = az[j2];
      }
      if (nw == 0 && (lane&15) == 1) {
        for (int j2 = 0; j2 < 4; ++j2) zp[1][r0+j2] = az[j2];
      }
      if (nw == 1 && (lane&15) == 0) {
        for (int j2 = 0; j2 < 4; ++j2) zp[2][r0+j2] = az[j2];
      }
    }
    __syncthreads();
    {
      // epilogue layer 1 (zb==1); znew computed inline per-thread
      float zs = zp[0][er] + zp[1][er] + zp[2][er] + bz1;
      float zn = fminf(fmaxf((zs + 1.f)*0.5f, 0.f), 1.f);
      float4 sv = *(const float4*)&ls_s[er][4*eu];
      float4 bb = *(const float4*)&bp1[ntg*128 + 4*eu];
      float f = sigmoidf_(sv.x + bb.x);
      float i = sigmoidf_(sv.y + bb.y);
      float o = sigmoidf_(sv.z + bb.z);
      float g = tanhf(sv.w + bb.w);
      float z = z1p;
      float ig = i * g;
      float cn = z * ig + (1.f - z) * fmaf(f, c1r, ig);
      float hn = o * tanhf(cn);
      c1r = cn;
      z1c = zn; z1p = zn;
      u16* a1w = A1b[p ^ 1];
      split_st_uc(a1w + pidx, a1w + PLSTR + pidx, (1.f - zn) * hn);   // A next step
      split_st_uc(B2b + pidx, B2b + PLSTR + pidx, zn * hn);           // B this step
    }
    #pragma unroll
    for (int kk = 0; kk < 4; ++kk) {   // preload phase-B weights (latency hides in drain+barrier)
      preh[kk] = *(const bf16x8*)(wbB + kk*1024);
      prel[kk] = *(const bf16x8*)(wbB + kk*1024 + 512);
    }
    drain_vmem();      // asm stores are outside the compiler's waitcnt tracking
    __syncthreads();   // all waves' stores at coherence point before arrival
    if (tid == 0) {
      __hip_atomic_fetch_add(cnt, 1u, __ATOMIC_RELAXED, __HIP_MEMORY_SCOPE_AGENT);
      while (__hip_atomic_load(cnt, __ATOMIC_RELAXED, __HIP_MEMORY_SCOPE_AGENT) < bar_tgt)
        __builtin_amdgcn_s_sleep(1);
    }
    bar_tgt += 16u;
    __builtin_amdgcn_s_barrier();

    // ======== PHASE B ========
    for (int j = 0; j < 4; ++j) {   // stage B2 (phase-A writes, fenced by barrier#1)
      int i = nw*4 + j; int spl = i >> 4, kq = i & 15;
      const u16* src = B2b + spl*PLSTR + ((size_t)((kq*4 + kgp)*256 + b0 + row16))*8;
      gload_lds16_uc(src, &stgB[1][spl][kq][0][0]);
    }
    for (int j = 0; j < 4; ++j) {   // prefetch A1[p^1] (phase-A writes, fenced by barrier#1)
      int i = nw*4 + j; int spl = i >> 4, kq = i & 15;
      const u16* src = A1b[p ^ 1] + spl*PLSTR + ((size_t)((kq*4 + kgp)*256 + b0 + row16))*8;
      gload_lds16_uc(src, &stgA[0][spl][kq][0][0]);
    }
    __syncthreads();

    {
      f32x4 acc0={0,0,0,0}, acc1={0,0,0,0}, acc2={0,0,0,0};
      f32x4 az={0,0,0,0};
      #pragma unroll
      for (int kb = 0; kb < 4; ++kb) {       // preloaded weights (cross-barrier)
        const u16* sa = &stgB[0][0][kb][lane][0];
        bf16x8 ah = *(const bf16x8*)sa;
        bf16x8 al = *(const bf16x8*)(sa + 8192);
        acc0 = __builtin_amdgcn_mfma_f32_16x16x32_bf16(ah, preh[kb], acc0, 0, 0, 0);
        acc1 = __builtin_amdgcn_mfma_f32_16x16x32_bf16(ah, prel[kb], acc1, 0, 0, 0);
        acc2 = __builtin_amdgcn_mfma_f32_16x16x32_bf16(al, preh[kb], acc2, 0, 0, 0);
        if (nw == 0) { bf16x8 zf = *(const bf16x8*)(wzB + kb*512);
                       az = __builtin_amdgcn_mfma_f32_16x16x32_bf16(ah, zf, az, 0, 0, 0); }
        if (nw == 1) { bf16x8 zf = *(const bf16x8*)(wzB + kb*512);
                       az = __builtin_amdgcn_mfma_f32_16x16x32_bf16(al, zf, az, 0, 0, 0); }
      }
      #pragma unroll 8
      for (int kb = 4; kb < 32; ++kb) {
        const u16* sa = &stgB[kb>>4][0][kb&15][lane][0];
        bf16x8 ah = *(const bf16x8*)sa;
        bf16x8 al = *(const bf16x8*)(sa + 8192);
        bf16x8 wh = *(const bf16x8*)(wbB + kb*1024);
        bf16x8 wl = *(const bf16x8*)(wbB + kb*1024 + 512);
        acc0 = __builtin_amdgcn_mfma_f32_16x16x32_bf16(ah, wh, acc0, 0, 0, 0);
        acc1 = __builtin_amdgcn_mfma_f32_16x16x32_bf16(ah, wl, acc1, 0, 0, 0);
        acc2 = __builtin_amdgcn_mfma_f32_16x16x32_bf16(al, wh, acc2, 0, 0, 0);
        if (nw == 0) { bf16x8 zf = *(const bf16x8*)(wzB + kb*512);
                       az = __builtin_amdgcn_mfma_f32_16x16x32_bf16(ah, zf, az, 0, 0, 0); }
        if (nw == 1) { bf16x8 zf = *(const bf16x8*)(wzB + kb*512);
                       az = __builtin_amdgcn_mfma_f32_16x16x32_bf16(al, zf, az, 0, 0, 0); }
      }
      f32x4 accs = acc0 + acc1; accs = accs + acc2;
      int cc = nw*16 + (lane & 15);
      int r0 = (lane >> 4) * 4;
      ls_s[r0+0][cc] = accs[0]; ls_s[r0+1][cc] = accs[1];
      ls_s[r0+2][cc] = accs[2]; ls_s[r0+3][cc] = accs[3];
      if (nw == 0 && (lane&15) == 0) {
        for (int j2 = 0; j2 < 4; ++j2) zp[0][r0+j2] = az[j2];
      }
      if (nw == 0 && (lane&15) == 1) {
        for (int j2 = 0; j2 < 4; ++j2) zp[1][r0+j2] = az[j2];
      }
      if (nw == 1 && (lane&15) == 0) {
        for (int j2 = 0; j2 < 4; ++j2) zp[2][r0+j2] = az[j2];
      }
    }
    __syncthreads();
    {
      // epilogue layer 2: z = z2(t-1), zb = z1(t); znew inline
      float zs = zp[0][er] + zp[1][er] + zp[2][er] + bz2;
      float z2n_ = fminf(fmaxf((zs + 1.f)*0.5f, 0.f), 1.f);
      float4 sv = *(const float4*)&ls_s[er][4*eu];
      float4 bb = *(const float4*)&bp2[ntg*128 + 4*eu];
      float f = sigmoidf_(sv.x + bb.x);
      float i = sigmoidf_(sv.y + bb.y);
      float o = sigmoidf_(sv.z + bb.z);
      float g = tanhf(sv.w + bb.w);
      float z = z2p, zb = z1c;
      float ig = i * g;
      float cn = z*ig + (1.f-z)*(1.f-zb)*c2r + (1.f-z)*zb*fmaf(f, c2r, ig);
      float tc = tanhf(cn);
      float ot = o * tc;
      float hn = z*ot + (1.f-z)*(1.f-zb)*h2r + (1.f-z)*zb*ot;
      c2r = cn; h2r = hn;
      z2p = z2n_;
      y[((size_t)erow * TT + t) * HH + ku] = hn * z2n_;
      u16* b1w = B1b[p ^ 1];
      split_st_uc(b1w + pidx, b1w + PLSTR + pidx, (1.f - z2n_) * hn);  // B next step
      split_st_uc(A2b + pidx, A2b + PLSTR + pidx, z1c * hn);           // A next step
    }
    #pragma unroll
    for (int kk = 0; kk < 4; ++kk) {   // preload next phase-A weights
      preh[kk] = *(const bf16x8*)(wbA + kk*1024);
      prel[kk] = *(const bf16x8*)(wbA + kk*1024 + 512);
    }
    drain_vmem();
    __syncthreads();   // all waves' stores at coherence point before arrival
    if (tid == 0) {
      __hip_atomic_fetch_add(cnt, 1u, __ATOMIC_RELAXED, __HIP_MEMORY_SCOPE_AGENT);
      while (__hip_atomic_load(cnt, __ATOMIC_RELAXED, __HIP_MEMORY_SCOPE_AGENT) < bar_tgt)
        __builtin_amdgcn_s_sleep(1);
    }
    bar_tgt += 16u;
    __builtin_amdgcn_s_barrier();

    p ^= 1;
  }
}

extern "C" void kernel_launch(void* const* d_in, const int* in_sizes, int n_in,
                              void* d_out, int out_size, void* d_ws, size_t ws_size,
                              hipStream_t stream) {
  const float* x     = (const float*)d_in[0];
  const float* U11_1 = (const float*)d_in[1];
  const float* U21_1 = (const float*)d_in[2];
  const float* W01_1 = (const float*)d_in[3];
  const float* b1    = (const float*)d_in[4];
  const float* U11_2 = (const float*)d_in[5];
  const float* W01_2 = (const float*)d_in[6];
  const float* b2    = (const float*)d_in[7];
  char*  wsb = (char*)d_ws;
  float* y   = (float*)d_out;
  (void)in_sizes; (void)n_in; (void)out_size; (void)ws_size;

  u16* wp    = (u16*)(wsb + OFF_WPA);
  u16* wzfa  = (u16*)(wsb + OFF_WZFA);
  u16* wzfb  = (u16*)(wsb + OFF_WZFB);
  float* bp1 = (float*)(wsb + OFF_BP1);
  float* bp2 = (float*)(wsb + OFF_BP2);
  float* bz  = (float*)(wsb + OFF_BZ);

  const unsigned NW = 128u*NKA*2u*512u + 128u*NKB*2u*512u;
  hipLaunchKernelGGL(pack_w, dim3((NW + 255u)/256u), dim3(256), 0, stream,
                     U11_1, U21_1, W01_1, U11_2, W01_2, wp);
  const unsigned NZ = 36u*512u + 32u*512u;
  hipLaunchKernelGGL(pack_wz, dim3((NZ + 255u)/256u), dim3(256), 0, stream,
                     U11_1, U21_1, W01_1, U11_2, W01_2, wzfa, wzfb);
  hipLaunchKernelGGL(pack_bias, dim3(17), dim3(256), 0, stream, b1, b2, bp1, bp2, bz);
  const unsigned n_zero_words = (unsigned)((OFF_END - OFF_CNT) / 4u);
  hipLaunchKernelGGL(init_zero, dim3((n_zero_words + 255u)/256u), dim3(256), 0, stream, wsb);

  const float* xq = x;
  char* wsq = wsb;
  float* yq = y;
  void* kargs[] = { (void*)&xq, (void*)&wsq, (void*)&yq };
  hipLaunchCooperativeKernel((void*)hmlstm_kernel, dim3(256), dim3(512), kargs, 0, stream);
}

// Round 14
// 40113.562 us; speedup vs baseline: 1.1861x; 1.0006x over previous
//
#include <hip/hip_runtime.h>

#define TT 512
#define BB 256
#define DD 128
#define HH 512
#define KA 1152
#define KB 1024
#define NKA 36
#define NKB 32

// ---- ws byte-offset layout ----
#define OFF_WPA  0ull
#define SZ_WPA   (128ull*NKA*2ull*512ull*2ull)     // [colblk][kb][spl][lane][8] bf16
#define OFF_WPB  (OFF_WPA + SZ_WPA)
#define SZ_WPB   (128ull*NKB*2ull*512ull*2ull)
#define OFF_WZFA (OFF_WPB + SZ_WPB)                // [kb][lane][8] u16 (col0=hi,col1=lo)
#define SZ_WZFA  (36ull*512ull*2ull)
#define OFF_WZFB (OFF_WZFA + SZ_WZFA)
#define SZ_WZFB  (32ull*512ull*2ull)
#define OFF_BP1  (OFF_WZFB + SZ_WZFB)              // f32[2048] permuted bias l1
#define OFF_BP2  (OFF_BP1 + 8192ull)
#define OFF_BZ   (OFF_BP2 + 8192ull)               // bz1, bz2
#define OFF_CNT  (OFF_BZ + 256ull)                 // 16 group counters, 256B apart
#define OFF_A1   (OFF_CNT + 4096ull)               // 2 bufs x [2spl][64kg][256row][8] u16
#define OFF_A2   (OFF_A1 + 2ull*524288ull)         // 1 buf
#define OFF_B1   (OFF_A2 + 524288ull)              // 2 bufs
#define OFF_B2   (OFF_B1 + 2ull*524288ull)         // 1 buf
#define OFF_END  (OFF_B2 + 524288ull)

#define PLSTR 131072   // u16 stride between split planes within an act buffer

typedef __bf16 bf16x8 __attribute__((ext_vector_type(8)));
typedef float  f32x4  __attribute__((ext_vector_type(4)));
typedef unsigned short u16;

__device__ __forceinline__ u16 bf_bits(__bf16 h) {
  union { __bf16 b; u16 u; } cv; cv.b = h; return cv.u;
}
__device__ __forceinline__ float sigmoidf_(float v) { return 1.f / (1.f + __expf(-v)); }

// uncached (device-coherent) u16 store: sc0 sc1 -> write-through to coherence point
__device__ __forceinline__ void st_uc(u16* p, u16 v) {
  unsigned vv = v;
  asm volatile("global_store_short %0, %1, off sc0 sc1" :: "v"(p), "v"(vv) : "memory");
}
__device__ __forceinline__ void split_st_uc(u16* hi, u16* lo, float v) {
  __bf16 h = (__bf16)v;
  __bf16 l = (__bf16)(v - (float)h);
  st_uc(hi, bf_bits(h));
  st_uc(lo, bf_bits(l));
}
// explicit drain of ALL outstanding VMEM ops of this wave (inline-asm stores are
// invisible to the compiler's waitcnt scoreboard -- __syncthreads alone is not enough)
__device__ __forceinline__ void drain_vmem() {
  asm volatile("s_waitcnt vmcnt(0)" ::: "memory");
}

// global->LDS DMA, 16B/lane, cpol aux = SC0|NT|SC1 = 19 (device-coherent read; R7-proven)
__device__ __forceinline__ void gload_lds16_uc(const void* g, void* l) {
  __builtin_amdgcn_global_load_lds((const __attribute__((address_space(1))) unsigned int*)g,
                                   (__attribute__((address_space(3))) unsigned int*)l, 16, 0, 19);
}

// ---------------- pack kernels (identical layouts to R5/R7) ----------------
__global__ void pack_w(const float* __restrict__ U11_1, const float* __restrict__ U21_1,
                       const float* __restrict__ W01_1, const float* __restrict__ U11_2,
                       const float* __restrict__ W01_2, u16* __restrict__ wp) {
  unsigned i = blockIdx.x * 256u + threadIdx.x;
  const unsigned NWA = 128u * NKA * 2u * 512u;
  const unsigned NWB = 128u * NKB * 2u * 512u;
  if (i >= NWA + NWB) return;
  float w; unsigned s;
  if (i < NWA) {
    unsigned lane = (i >> 3) & 63u, e = i & 7u; s = (i >> 9) & 1u;
    unsigned blk = i >> 10, kb = blk % NKA, colblk = blk / NKA;
    unsigned c = colblk * 16u + (lane & 15u);
    unsigned n = (c & 3u) * 512u + (c >> 2);
    unsigned k = kb * 32u + (lane >> 4) * 8u + e;
    w = (k < 512u)  ? U11_1[n * 512u + k]
      : (k < 1024u) ? U21_1[n * 512u + (k - 512u)]
                    : W01_1[n * 128u + (k - 1024u)];
  } else {
    unsigned j = i - NWA;
    unsigned lane = (j >> 3) & 63u, e = j & 7u; s = (j >> 9) & 1u;
    unsigned blk = j >> 10, kb = blk % NKB, colblk = blk / NKB;
    unsigned c = colblk * 16u + (lane & 15u);
    unsigned n = (c & 3u) * 512u + (c >> 2);
    unsigned k = kb * 32u + (lane >> 4) * 8u + e;
    w = (k < 512u) ? U11_2[n * 512u + k] : W01_2[n * 512u + (k - 512u)];
  }
  __bf16 hi = (__bf16)w;
  __bf16 v = s ? (__bf16)(w - (float)hi) : hi;
  wp[i] = bf_bits(v);
}

__global__ void pack_wz(const float* __restrict__ U11_1, const float* __restrict__ U21_1,
                        const float* __restrict__ W01_1, const float* __restrict__ U11_2,
                        const float* __restrict__ W01_2,
                        u16* __restrict__ wzfa, u16* __restrict__ wzfb) {
  unsigned i = blockIdx.x * 256u + threadIdx.x;
  const unsigned NZA = 36u * 512u, NZB = 32u * 512u;
  if (i >= NZA + NZB) return;
  const bool isA = i < NZA;
  unsigned j = isA ? i : i - NZA;
  unsigned e = j & 7u, lane = (j >> 3) & 63u, kb = j >> 9;
  unsigned col = lane & 15u;
  unsigned k = kb * 32u + (lane >> 4) * 8u + e;
  float wz;
  if (isA) {
    wz = (k < 512u)  ? U11_1[2048u*512u + k]
       : (k < 1024u) ? U21_1[2048u*512u + (k-512u)]
                     : W01_1[2048u*128u + (k-1024u)];
  } else {
    wz = (k < 512u) ? U11_2[2048u*512u + k] : W01_2[2048u*512u + (k-512u)];
  }
  u16 out = 0;
  if (col == 0u) out = bf_bits((__bf16)wz);
  else if (col == 1u) { __bf16 h = (__bf16)wz; out = bf_bits((__bf16)(wz - (float)h)); }
  (isA ? wzfa : wzfb)[j] = out;
}

__global__ void pack_bias(const float* __restrict__ b1, const float* __restrict__ b2,
                          float* __restrict__ bp1, float* __restrict__ bp2,
                          float* __restrict__ bz) {
  unsigned i = blockIdx.x * 256u + threadIdx.x;
  if (i < 2048u) bp1[i] = b1[(i & 3u)*512u + (i >> 2)];
  else if (i < 4096u) { unsigned c = i - 2048u; bp2[c] = b2[(c & 3u)*512u + (c >> 2)]; }
  else if (i == 4096u) bz[0] = b1[2048];
  else if (i == 4097u) bz[1] = b2[2048];
}

// zero act buffers + counters
__global__ void init_zero(char* __restrict__ wsb) {
  size_t i = (size_t)blockIdx.x * 256u + threadIdx.x;
  size_t n = (OFF_END - OFF_CNT) / 4u;
  if (i < n) ((unsigned*)(wsb + OFF_CNT))[i] = 0u;
}

// ---------------- main persistent kernel ----------------
// R7-proven structure: 256 WGs x 512 threads (cooperative), WG = 16 rows x 128 cols,
// XCD x hosts ntg {2x,2x+1} for all 16 mgs -> 2.2 MB L2-resident weights.
// 16 independent group barriers (counter + tid0 relaxed agent RMW/poll);
// release = drain_vmem + __syncthreads. This round adds ONLY scheduling changes:
// launch_bounds(512,1) (256-VGPR budget; LDS already caps at 1 WG/CU), unroll 8,
// and cross-barrier preload of the next phase's first 4 K-blocks of weights
// (constants -> no coherence dependency; latency hides under drain+barrier).
__global__ __launch_bounds__(512, 1) void hmlstm_kernel(const float* __restrict__ x,
                                                        char* __restrict__ wsb,
                                                        float* __restrict__ y) {
  const int tid  = threadIdx.x;
  const int lane = tid & 63;
  const int nw   = __builtin_amdgcn_readfirstlane(tid >> 6);
  const int bid  = blockIdx.x;
  const int ntg  = (bid & 7) * 2 + (bid >> 7);   // 0..15
  const int mg   = (bid >> 3) & 15;              // 0..15
  const int b0   = mg * 16;

  const u16* wpA  = (const u16*)(wsb + OFF_WPA);
  const u16* wpB  = (const u16*)(wsb + OFF_WPB);
  const u16* wzfA = (const u16*)(wsb + OFF_WZFA);
  const u16* wzfB = (const u16*)(wsb + OFF_WZFB);
  const float* bp1 = (const float*)(wsb + OFF_BP1);
  const float* bp2 = (const float*)(wsb + OFF_BP2);
  const float bz1 = ((const float*)(wsb + OFF_BZ))[0];
  const float bz2 = ((const float*)(wsb + OFF_BZ))[1];
  unsigned* cnt = (unsigned*)(wsb + OFF_CNT) + mg * 64;   // own 256B line
  u16* A1b[2] = { (u16*)(wsb + OFF_A1), (u16*)(wsb + OFF_A1 + 524288ull) };
  u16* A2b    =   (u16*)(wsb + OFF_A2);
  u16* B1b[2] = { (u16*)(wsb + OFF_B1), (u16*)(wsb + OFF_B1 + 524288ull) };
  u16* B2b    =   (u16*)(wsb + OFF_B2);

  __shared__ u16 stgA[2][2][16][64][8];   // 64 KB
  __shared__ u16 stgB[2][2][16][64][8];   // 64 KB
  __shared__ float ls_s[16][132];
  __shared__ float zp[3][16];

  const int kgp   = lane >> 4;    // k-slot 0..3
  const int row16 = lane & 15;    // frag row 0..15
  const int er = tid >> 5, eu = tid & 31;   // epilogue (row, unit-in-WG)
  const int erow = b0 + er;
  const int ku = ntg * 32 + eu;             // global hidden-unit index
  const size_t pidx = ((size_t)(ku >> 3) * 256 + erow) * 8 + (ku & 7);

  const u16* wbA = wpA + (size_t)(ntg*8 + nw) * (NKA*1024u) + lane*8;
  const u16* wbB = wpB + (size_t)(ntg*8 + nw) * (NKB*1024u) + lane*8;
  const u16* wzA = wzfA + lane*8;
  const u16* wzB = wzfB + lane*8;

  // per-thread recurrent state (row er, unit eu fixed across steps)
  float c1r = 0.f, c2r = 0.f, h2r = 0.f;
  float z1p = 0.f, z2p = 0.f, z1c = 0.f;
  unsigned bar_tgt = 16u;
  int p = 0;

  // cross-barrier weight preload registers (next phase's kb 0..3)
  bf16x8 preh[4], prel[4];
  #pragma unroll
  for (int kk = 0; kk < 4; ++kk) {       // prime for phase A of t=0
    preh[kk] = *(const bf16x8*)(wbA + kk*1024);
    prel[kk] = *(const bf16x8*)(wbA + kk*1024 + 512);
  }

  for (int t = 0; t < TT; ++t) {
    // ======== PHASE A ========
    if (t == 0) {   // no prior prefetch of A1[0]
      for (int j = 0; j < 4; ++j) {
        int i = nw*4 + j; int spl = i >> 4, kq = i & 15;
        const u16* src = A1b[0] + spl*PLSTR + ((size_t)((kq*4 + kgp)*256 + b0 + row16))*8;
        gload_lds16_uc(src, &stgA[0][spl][kq][0][0]);
      }
    }
    for (int j = 0; j < 4; ++j) {     // stage A2 half (fenced by barrier#2 of t-1)
      int i = nw*4 + j; int spl = i >> 4, kq = i & 15;
      const u16* src = A2b + spl*PLSTR + ((size_t)((kq*4 + kgp)*256 + b0 + row16))*8;
      gload_lds16_uc(src, &stgA[1][spl][kq][0][0]);
    }
    for (int j = 0; j < 4; ++j) {     // prefetch B1[p] (fenced by barrier#2 of t-1)
      int i = nw*4 + j; int spl = i >> 4, kq = i & 15;
      const u16* src = B1b[p] + spl*PLSTR + ((size_t)((kq*4 + kgp)*256 + b0 + row16))*8;
      gload_lds16_uc(src, &stgB[0][spl][kq][0][0]);
    }
    // x fragments on the fly (cached f32 reads, static input)
    bf16x8 xah[4], xal[4];
    {
      const float* xp = x + ((size_t)(b0 + row16) * TT + t) * DD + kgp*8;
      for (int k4 = 0; k4 < 4; ++k4) {
        float4 v0 = *(const float4*)(xp + k4*32);
        float4 v1 = *(const float4*)(xp + k4*32 + 4);
        float vv[8] = {v0.x,v0.y,v0.z,v0.w,v1.x,v1.y,v1.z,v1.w};
        for (int e = 0; e < 8; ++e) {
          __bf16 h = (__bf16)vv[e];
          xah[k4][e] = h;
          xal[k4][e] = (__bf16)(vv[e] - (float)h);
        }
      }
    }
    __syncthreads();   // drain staging DMAs + WG barrier

    {
      f32x4 acc0={0,0,0,0}, acc1={0,0,0,0}, acc2={0,0,0,0};
      f32x4 az={0,0,0,0};
      #pragma unroll
      for (int kb = 0; kb < 4; ++kb) {       // preloaded weights (cross-barrier)
        const u16* sa = &stgA[0][0][kb][lane][0];
        bf16x8 ah = *(const bf16x8*)sa;
        bf16x8 al = *(const bf16x8*)(sa + 8192);
        acc0 = __builtin_amdgcn_mfma_f32_16x16x32_bf16(ah, preh[kb], acc0, 0, 0, 0);
        acc1 = __builtin_amdgcn_mfma_f32_16x16x32_bf16(ah, prel[kb], acc1, 0, 0, 0);
        acc2 = __builtin_amdgcn_mfma_f32_16x16x32_bf16(al, preh[kb], acc2, 0, 0, 0);
        if (nw == 0) { bf16x8 zf = *(const bf16x8*)(wzA + kb*512);
                       az = __builtin_amdgcn_mfma_f32_16x16x32_bf16(ah, zf, az, 0, 0, 0); }
        if (nw == 1) { bf16x8 zf = *(const bf16x8*)(wzA + kb*512);
                       az = __builtin_amdgcn_mfma_f32_16x16x32_bf16(al, zf, az, 0, 0, 0); }
      }
      #pragma unroll 8
      for (int kb = 4; kb < 32; ++kb) {
        const u16* sa = &stgA[kb>>4][0][kb&15][lane][0];
        bf16x8 ah = *(const bf16x8*)sa;
        bf16x8 al = *(const bf16x8*)(sa + 8192);
        bf16x8 wh = *(const bf16x8*)(wbA + kb*1024);
        bf16x8 wl = *(const bf16x8*)(wbA + kb*1024 + 512);
        acc0 = __builtin_amdgcn_mfma_f32_16x16x32_bf16(ah, wh, acc0, 0, 0, 0);
        acc1 = __builtin_amdgcn_mfma_f32_16x16x32_bf16(ah, wl, acc1, 0, 0, 0);
        acc2 = __builtin_amdgcn_mfma_f32_16x16x32_bf16(al, wh, acc2, 0, 0, 0);
        if (nw == 0) { bf16x8 zf = *(const bf16x8*)(wzA + kb*512);
                       az = __builtin_amdgcn_mfma_f32_16x16x32_bf16(ah, zf, az, 0, 0, 0); }
        if (nw == 1) { bf16x8 zf = *(const bf16x8*)(wzA + kb*512);
                       az = __builtin_amdgcn_mfma_f32_16x16x32_bf16(al, zf, az, 0, 0, 0); }
      }
      for (int k4 = 0; k4 < 4; ++k4) {
        int kb = 32 + k4;
        bf16x8 ah = xah[k4], al = xal[k4];
        bf16x8 wh = *(const bf16x8*)(wbA + kb*1024);
        bf16x8 wl = *(const bf16x8*)(wbA + kb*1024 + 512);
        acc0 = __builtin_amdgcn_mfma_f32_16x16x32_bf16(ah, wh, acc0, 0, 0, 0);
        acc1 = __builtin_amdgcn_mfma_f32_16x16x32_bf16(ah, wl, acc1, 0, 0, 0);
        acc2 = __builtin_amdgcn_mfma_f32_16x16x32_bf16(al, wh, acc2, 0, 0, 0);
        if (nw == 0) { bf16x8 zf = *(const bf16x8*)(wzA + kb*512);
                       az = __builtin_amdgcn_mfma_f32_16x16x32_bf16(ah, zf, az, 0, 0, 0); }
        if (nw == 1) { bf16x8 zf = *(const bf16x8*)(wzA + kb*512);
                       az = __builtin_amdgcn_mfma_f32_16x16x32_bf16(al, zf, az, 0, 0, 0); }
      }
      f32x4 accs = acc0 + acc1; accs = accs + acc2;
      int cc = nw*16 + (lane & 15);
      int r0 = (lane >> 4) * 4;
      ls_s[r0+0][cc] = accs[0]; ls_s[r0+1][cc] = accs[1];
      ls_s[r0+2][cc] = accs[2]; ls_s[r0+3][cc] = accs[3];
      if (nw == 0 && (lane&15) == 0) {
        for (int j2 = 0; j2 < 4; ++j2) zp[0][r0+j2] = az[j2];
      }
      if (nw == 0 && (lane&15) == 1) {
        for (int j2 = 0; j2 < 4; ++j2) zp[1][r0+j2] = az[j2];
      }
      if (nw == 1 && (lane&15) == 0) {
        for (int j2 = 0; j2 < 4; ++j2) zp[2][r0+j2] = az[j2];
      }
    }
    __syncthreads();
    {
      // epilogue layer 1 (zb==1); znew computed inline per-thread
      float zs = zp[0][er] + zp[1][er] + zp[2][er] + bz1;
      float zn = fminf(fmaxf((zs + 1.f)*0.5f, 0.f), 1.f);
      float4 sv = *(const float4*)&ls_s[er][4*eu];
      float4 bb = *(const float4*)&bp1[ntg*128 + 4*eu];
      float f = sigmoidf_(sv.x + bb.x);
      float i = sigmoidf_(sv.y + bb.y);
      float o = sigmoidf_(sv.z + bb.z);
      float g = tanhf(sv.w + bb.w);
      float z = z1p;
      float ig = i * g;
      float cn = z * ig + (1.f - z) * fmaf(f, c1r, ig);
      float hn = o * tanhf(cn);
      c1r = cn;
      z1c = zn; z1p = zn;
      u16* a1w = A1b[p ^ 1];
      split_st_uc(a1w + pidx, a1w + PLSTR + pidx, (1.f - zn) * hn);   // A next step
      split_st_uc(B2b + pidx, B2b + PLSTR + pidx, zn * hn);           // B this step
    }
    #pragma unroll
    for (int kk = 0; kk < 4; ++kk) {   // preload phase-B weights (latency hides in drain+barrier)
      preh[kk] = *(const bf16x8*)(wbB + kk*1024);
      prel[kk] = *(const bf16x8*)(wbB + kk*1024 + 512);
    }
    drain_vmem();      // asm stores are outside the compiler's waitcnt tracking
    __syncthreads();   // all waves' stores at coherence point before arrival
    if (tid == 0) {
      __hip_atomic_fetch_add(cnt, 1u, __ATOMIC_RELAXED, __HIP_MEMORY_SCOPE_AGENT);
      while (__hip_atomic_load(cnt, __ATOMIC_RELAXED, __HIP_MEMORY_SCOPE_AGENT) < bar_tgt)
        __builtin_amdgcn_s_sleep(1);
    }
    bar_tgt += 16u;
    __builtin_amdgcn_s_barrier();

    // ======== PHASE B ========
    for (int j = 0; j < 4; ++j) {   // stage B2 (phase-A writes, fenced by barrier#1)
      int i = nw*4 + j; int spl = i >> 4, kq = i & 15;
      const u16* src = B2b + spl*PLSTR + ((size_t)((kq*4 + kgp)*256 + b0 + row16))*8;
      gload_lds16_uc(src, &stgB[1][spl][kq][0][0]);
    }
    for (int j = 0; j < 4; ++j) {   // prefetch A1[p^1] (phase-A writes, fenced by barrier#1)
      int i = nw*4 + j; int spl = i >> 4, kq = i & 15;
      const u16* src = A1b[p ^ 1] + spl*PLSTR + ((size_t)((kq*4 + kgp)*256 + b0 + row16))*8;
      gload_lds16_uc(src, &stgA[0][spl][kq][0][0]);
    }
    __syncthreads();

    {
      f32x4 acc0={0,0,0,0}, acc1={0,0,0,0}, acc2={0,0,0,0};
      f32x4 az={0,0,0,0};
      #pragma unroll
      for (int kb = 0; kb < 4; ++kb) {       // preloaded weights (cross-barrier)
        const u16* sa = &stgB[0][0][kb][lane][0];
        bf16x8 ah = *(const bf16x8*)sa;
        bf16x8 al = *(const bf16x8*)(sa + 8192);
        acc0 = __builtin_amdgcn_mfma_f32_16x16x32_bf16(ah, preh[kb], acc0, 0, 0, 0);
        acc1 = __builtin_amdgcn_mfma_f32_16x16x32_bf16(ah, prel[kb], acc1, 0, 0, 0);
        acc2 = __builtin_amdgcn_mfma_f32_16x16x32_bf16(al, preh[kb], acc2, 0, 0, 0);
        if (nw == 0) { bf16x8 zf = *(const bf16x8*)(wzB + kb*512);
                       az = __builtin_amdgcn_mfma_f32_16x16x32_bf16(ah, zf, az, 0, 0, 0); }
        if (nw == 1) { bf16x8 zf = *(const bf16x8*)(wzB + kb*512);
                       az = __builtin_amdgcn_mfma_f32_16x16x32_bf16(al, zf, az, 0, 0, 0); }
      }
      #pragma unroll 8
      for (int kb = 4; kb < 32; ++kb) {
        const u16* sa = &stgB[kb>>4][0][kb&15][lane][0];
        bf16x8 ah = *(const bf16x8*)sa;
        bf16x8 al = *(const bf16x8*)(sa + 8192);
        bf16x8 wh = *(const bf16x8*)(wbB + kb*1024);
        bf16x8 wl = *(const bf16x8*)(wbB + kb*1024 + 512);
        acc0 = __builtin_amdgcn_mfma_f32_16x16x32_bf16(ah, wh, acc0, 0, 0, 0);
        acc1 = __builtin_amdgcn_mfma_f32_16x16x32_bf16(ah, wl, acc1, 0, 0, 0);
        acc2 = __builtin_amdgcn_mfma_f32_16x16x32_bf16(al, wh, acc2, 0, 0, 0);
        if (nw == 0) { bf16x8 zf = *(const bf16x8*)(wzB + kb*512);
                       az = __builtin_amdgcn_mfma_f32_16x16x32_bf16(ah, zf, az, 0, 0, 0); }
        if (nw == 1) { bf16x8 zf = *(const bf16x8*)(wzB + kb*512);
                       az = __builtin_amdgcn_mfma_f32_16x16x32_bf16(al, zf, az, 0, 0, 0); }
      }
      f32x4 accs = acc0 + acc1; accs = accs + acc2;
      int cc = nw*16 + (lane & 15);
      int r0 = (lane >> 4) * 4;
      ls_s[r0+0][cc] = accs[0]; ls_s[r0+1][cc] = accs[1];
      ls_s[r0+2][cc] = accs[2]; ls_s[r0+3][cc] = accs[3];
      if (nw == 0 && (lane&15) == 0) {
        for (int j2 = 0; j2 < 4; ++j2) zp[0][r0+j2] = az[j2];
      }
      if (nw == 0 && (lane&15) == 1) {
        for (int j2 = 0; j2 < 4; ++j2) zp[1][r0+j2] = az[j2];
      }
      if (nw == 1 && (lane&15) == 0) {
        for (int j2 = 0; j2 < 4; ++j2) zp[2][r0+j2] = az[j2];
      }
    }
    __syncthreads();
    {
      // epilogue layer 2: z = z2(t-1), zb = z1(t); znew inline
      float zs = zp[0][er] + zp[1][er] + zp[2][er] + bz2;
      float z2n_ = fminf(fmaxf((zs + 1.f)*0.5f, 0.f), 1.f);
      float4 sv = *(const float4*)&ls_s[er][4*eu];
      float4 bb = *(const float4*)&bp2[ntg*128 + 4*eu];
      float f = sigmoidf_(sv.x + bb.x);
      float i = sigmoidf_(sv.y + bb.y);
      float o = sigmoidf_(sv.z + bb.z);
      float g = tanhf(sv.w + bb.w);
      float z = z2p, zb = z1c;
      float ig = i * g;
      float cn = z*ig + (1.f-z)*(1.f-zb)*c2r + (1.f-z)*zb*fmaf(f, c2r, ig);
      float tc = tanhf(cn);
      float ot = o * tc;
      float hn = z*ot + (1.f-z)*(1.f-zb)*h2r + (1.f-z)*zb*ot;
      c2r = cn; h2r = hn;
      z2p = z2n_;
      y[((size_t)erow * TT + t) * HH + ku] = hn * z2n_;
      u16* b1w = B1b[p ^ 1];
      split_st_uc(b1w + pidx, b1w + PLSTR + pidx, (1.f - z2n_) * hn);  // B next step
      split_st_uc(A2b + pidx, A2b + PLSTR + pidx, z1c * hn);           // A next step
    }
    #pragma unroll
    for (int kk = 0; kk < 4; ++kk) {   // preload next phase-A weights
      preh[kk] = *(const bf16x8*)(wbA + kk*1024);
      prel[kk] = *(const bf16x8*)(wbA + kk*1024 + 512);
    }
    drain_vmem();
    __syncthreads();   // all waves' stores at coherence point before arrival
    if (tid == 0) {
      __hip_atomic_fetch_add(cnt, 1u, __ATOMIC_RELAXED, __HIP_MEMORY_SCOPE_AGENT);
      while (__hip_atomic_load(cnt, __ATOMIC_RELAXED, __HIP_MEMORY_SCOPE_AGENT) < bar_tgt)
        __builtin_amdgcn_s_sleep(1);
    }
    bar_tgt += 16u;
    __builtin_amdgcn_s_barrier();

    p ^= 1;
  }
}

extern "C" void kernel_launch(void* const* d_in, const int* in_sizes, int n_in,
                              void* d_out, int out_size, void* d_ws, size_t ws_size,
                              hipStream_t stream) {
  const float* x     = (const float*)d_in[0];
  const float* U11_1 = (const float*)d_in[1];
  const float* U21_1 = (const float*)d_in[2];
  const float* W01_1 = (const float*)d_in[3];
  const float* b1    = (const float*)d_in[4];
  const float* U11_2 = (const float*)d_in[5];
  const float* W01_2 = (const float*)d_in[6];
  const float* b2    = (const float*)d_in[7];
  char*  wsb = (char*)d_ws;
  float* y   = (float*)d_out;
  (void)in_sizes; (void)n_in; (void)out_size; (void)ws_size;

  u16* wp    = (u16*)(wsb + OFF_WPA);
  u16* wzfa  = (u16*)(wsb + OFF_WZFA);
  u16* wzfb  = (u16*)(wsb + OFF_WZFB);
  float* bp1 = (float*)(wsb + OFF_BP1);
  float* bp2 = (float*)(wsb + OFF_BP2);
  float* bz  = (float*)(wsb + OFF_BZ);

  const unsigned NW = 128u*NKA*2u*512u + 128u*NKB*2u*512u;
  hipLaunchKernelGGL(pack_w, dim3((NW + 255u)/256u), dim3(256), 0, stream,
                     U11_1, U21_1, W01_1, U11_2, W01_2, wp);
  const unsigned NZ = 36u*512u + 32u*512u;
  hipLaunchKernelGGL(pack_wz, dim3((NZ + 255u)/256u), dim3(256), 0, stream,
                     U11_1, U21_1, W01_1, U11_2, W01_2, wzfa, wzfb);
  hipLaunchKernelGGL(pack_bias, dim3(17), dim3(256), 0, stream, b1, b2, bp1, bp2, bz);
  const unsigned n_zero_words = (unsigned)((OFF_END - OFF_CNT) / 4u);
  hipLaunchKernelGGL(init_zero, dim3((n_zero_words + 255u)/256u), dim3(256), 0, stream, wsb);

  const float* xq = x;
  char* wsq = wsb;
  float* yq = y;
  void* kargs[] = { (void*)&xq, (void*)&wsq, (void*)&yq };
  hipLaunchCooperativeKernel((void*)hmlstm_kernel, dim3(256), dim3(512), kargs, 0, stream);
}

// Round 15
// 15560.023 us; speedup vs baseline: 3.0578x; 2.5780x over previous
//
#include <hip/hip_runtime.h>

#define TT 512
#define BB 256
#define DD 128
#define HH 512
#define KA 1152
#define KB 1024
#define NKA 36
#define NKB 32

// ---- ws byte-offset layout ----
#define OFF_WPA  0ull
#define SZ_WPA   (128ull*NKA*2ull*512ull*2ull)     // [colblk][kb][spl][lane][8] bf16
#define OFF_WPB  (OFF_WPA + SZ_WPA)
#define SZ_WPB   (128ull*NKB*2ull*512ull*2ull)
#define OFF_WZFA (OFF_WPB + SZ_WPB)                // [kb][lane][8] u16 (col0=hi,col1=lo)
#define SZ_WZFA  (36ull*512ull*2ull)
#define OFF_WZFB (OFF_WZFA + SZ_WZFA)
#define SZ_WZFB  (32ull*512ull*2ull)
#define OFF_BP1  (OFF_WZFB + SZ_WZFB)              // f32[2048] permuted bias l1
#define OFF_BP2  (OFF_BP1 + 8192ull)
#define OFF_BZ   (OFF_BP2 + 8192ull)               // bz1, bz2
#define OFF_CNT  (OFF_BZ + 256ull)                 // 16 group counters, 256B apart
#define OFF_A1   (OFF_CNT + 4096ull)               // 2 bufs x [2spl][64kg][256row][8] u16
#define OFF_A2   (OFF_A1 + 2ull*524288ull)         // 1 buf
#define OFF_B1   (OFF_A2 + 524288ull)              // 2 bufs
#define OFF_B2   (OFF_B1 + 2ull*524288ull)         // 1 buf
#define OFF_END  (OFF_B2 + 524288ull)

#define PLSTR 131072   // u16 stride between split planes within an act buffer

typedef __bf16 bf16x8 __attribute__((ext_vector_type(8)));
typedef float  f32x4  __attribute__((ext_vector_type(4)));
typedef unsigned short u16;

__device__ __forceinline__ u16 bf_bits(__bf16 h) {
  union { __bf16 b; u16 u; } cv; cv.b = h; return cv.u;
}
__device__ __forceinline__ float sigmoidf_(float v) { return 1.f / (1.f + __expf(-v)); }

// uncached (device-coherent) u16 store: sc0 sc1 -> write-through to coherence point
__device__ __forceinline__ void st_uc(u16* p, u16 v) {
  unsigned vv = v;
  asm volatile("global_store_short %0, %1, off sc0 sc1" :: "v"(p), "v"(vv) : "memory");
}
__device__ __forceinline__ void split_st_uc(u16* hi, u16* lo, float v) {
  __bf16 h = (__bf16)v;
  __bf16 l = (__bf16)(v - (float)h);
  st_uc(hi, bf_bits(h));
  st_uc(lo, bf_bits(l));
}
// explicit drain of ALL outstanding VMEM ops of this wave (inline-asm stores are
// invisible to the compiler's waitcnt scoreboard -- __syncthreads alone is not enough)
__device__ __forceinline__ void drain_vmem() {
  asm volatile("s_waitcnt vmcnt(0)" ::: "memory");
}

// global->LDS DMA, 16B/lane, cpol aux = SC0|NT|SC1 = 19 (device-coherent read; R7-proven)
__device__ __forceinline__ void gload_lds16_uc(const void* g, void* l) {
  __builtin_amdgcn_global_load_lds((const __attribute__((address_space(1))) unsigned int*)g,
                                   (__attribute__((address_space(3))) unsigned int*)l, 16, 0, 19);
}

// ---------------- pack kernels (identical layouts to R5/R7) ----------------
__global__ void pack_w(const float* __restrict__ U11_1, const float* __restrict__ U21_1,
                       const float* __restrict__ W01_1, const float* __restrict__ U11_2,
                       const float* __restrict__ W01_2, u16* __restrict__ wp) {
  unsigned i = blockIdx.x * 256u + threadIdx.x;
  const unsigned NWA = 128u * NKA * 2u * 512u;
  const unsigned NWB = 128u * NKB * 2u * 512u;
  if (i >= NWA + NWB) return;
  float w; unsigned s;
  if (i < NWA) {
    unsigned lane = (i >> 3) & 63u, e = i & 7u; s = (i >> 9) & 1u;
    unsigned blk = i >> 10, kb = blk % NKA, colblk = blk / NKA;
    unsigned c = colblk * 16u + (lane & 15u);
    unsigned n = (c & 3u) * 512u + (c >> 2);
    unsigned k = kb * 32u + (lane >> 4) * 8u + e;
    w = (k < 512u)  ? U11_1[n * 512u + k]
      : (k < 1024u) ? U21_1[n * 512u + (k - 512u)]
                    : W01_1[n * 128u + (k - 1024u)];
  } else {
    unsigned j = i - NWA;
    unsigned lane = (j >> 3) & 63u, e = j & 7u; s = (j >> 9) & 1u;
    unsigned blk = j >> 10, kb = blk % NKB, colblk = blk / NKB;
    unsigned c = colblk * 16u + (lane & 15u);
    unsigned n = (c & 3u) * 512u + (c >> 2);
    unsigned k = kb * 32u + (lane >> 4) * 8u + e;
    w = (k < 512u) ? U11_2[n * 512u + k] : W01_2[n * 512u + (k - 512u)];
  }
  __bf16 hi = (__bf16)w;
  __bf16 v = s ? (__bf16)(w - (float)hi) : hi;
  wp[i] = bf_bits(v);
}

__global__ void pack_wz(const float* __restrict__ U11_1, const float* __restrict__ U21_1,
                        const float* __restrict__ W01_1, const float* __restrict__ U11_2,
                        const float* __restrict__ W01_2,
                        u16* __restrict__ wzfa, u16* __restrict__ wzfb) {
  unsigned i = blockIdx.x * 256u + threadIdx.x;
  const unsigned NZA = 36u * 512u, NZB = 32u * 512u;
  if (i >= NZA + NZB) return;
  const bool isA = i < NZA;
  unsigned j = isA ? i : i - NZA;
  unsigned e = j & 7u, lane = (j >> 3) & 63u, kb = j >> 9;
  unsigned col = lane & 15u;
  unsigned k = kb * 32u + (lane >> 4) * 8u + e;
  float wz;
  if (isA) {
    wz = (k < 512u)  ? U11_1[2048u*512u + k]
       : (k < 1024u) ? U21_1[2048u*512u + (k-512u)]
                     : W01_1[2048u*128u + (k-1024u)];
  } else {
    wz = (k < 512u) ? U11_2[2048u*512u + k] : W01_2[2048u*512u + (k-512u)];
  }
  u16 out = 0;
  if (col == 0u) out = bf_bits((__bf16)wz);
  else if (col == 1u) { __bf16 h = (__bf16)wz; out = bf_bits((__bf16)(wz - (float)h)); }
  (isA ? wzfa : wzfb)[j] = out;
}

__global__ void pack_bias(const float* __restrict__ b1, const float* __restrict__ b2,
                          float* __restrict__ bp1, float* __restrict__ bp2,
                          float* __restrict__ bz) {
  unsigned i = blockIdx.x * 256u + threadIdx.x;
  if (i < 2048u) bp1[i] = b1[(i & 3u)*512u + (i >> 2)];
  else if (i < 4096u) { unsigned c = i - 2048u; bp2[c] = b2[(c & 3u)*512u + (c >> 2)]; }
  else if (i == 4096u) bz[0] = b1[2048];
  else if (i == 4097u) bz[1] = b2[2048];
}

// zero act buffers + counters
__global__ void init_zero(char* __restrict__ wsb) {
  size_t i = (size_t)blockIdx.x * 256u + threadIdx.x;
  size_t n = (OFF_END - OFF_CNT) / 4u;
  if (i < n) ((unsigned*)(wsb + OFF_CNT))[i] = 0u;
}

// ---------------- main persistent kernel (exact R7 revert, 15.6 ms proven) ----------------
// 256 WGs x 512 threads. WG = 16 rows (mg) x 128 cols (ntg).
// XCD x (bid&7) hosts ntg {2x,2x+1} for all 16 mgs -> 2.2 MB L2-resident weights.
// Cross-WG deps exist ONLY within an mg-group (16 WGs sharing rows) -> 16
// independent group barriers (one counter per mg, own cache line). No L2
// invalidation anywhere; acts via device-coherent stores + coherent DMA reads.
// All inline-asm stores are explicitly drained (vmcnt0) before barrier arrival.
__global__ __launch_bounds__(512, 2) void hmlstm_kernel(const float* __restrict__ x,
                                                        char* __restrict__ wsb,
                                                        float* __restrict__ y) {
  const int tid  = threadIdx.x;
  const int lane = tid & 63;
  const int nw   = __builtin_amdgcn_readfirstlane(tid >> 6);
  const int bid  = blockIdx.x;
  const int ntg  = (bid & 7) * 2 + (bid >> 7);   // 0..15
  const int mg   = (bid >> 3) & 15;              // 0..15
  const int b0   = mg * 16;

  const u16* wpA  = (const u16*)(wsb + OFF_WPA);
  const u16* wpB  = (const u16*)(wsb + OFF_WPB);
  const u16* wzfA = (const u16*)(wsb + OFF_WZFA);
  const u16* wzfB = (const u16*)(wsb + OFF_WZFB);
  const float* bp1 = (const float*)(wsb + OFF_BP1);
  const float* bp2 = (const float*)(wsb + OFF_BP2);
  const float bz1 = ((const float*)(wsb + OFF_BZ))[0];
  const float bz2 = ((const float*)(wsb + OFF_BZ))[1];
  unsigned* cnt = (unsigned*)(wsb + OFF_CNT) + mg * 64;   // own 256B line
  u16* A1b[2] = { (u16*)(wsb + OFF_A1), (u16*)(wsb + OFF_A1 + 524288ull) };
  u16* A2b    =   (u16*)(wsb + OFF_A2);
  u16* B1b[2] = { (u16*)(wsb + OFF_B1), (u16*)(wsb + OFF_B1 + 524288ull) };
  u16* B2b    =   (u16*)(wsb + OFF_B2);

  __shared__ u16 stgA[2][2][16][64][8];   // 64 KB
  __shared__ u16 stgB[2][2][16][64][8];   // 64 KB
  __shared__ float ls_s[16][132];
  __shared__ float zp[3][16];

  const int kgp   = lane >> 4;    // k-slot 0..3
  const int row16 = lane & 15;    // frag row 0..15
  const int er = tid >> 5, eu = tid & 31;   // epilogue (row, unit-in-WG)
  const int erow = b0 + er;
  const int ku = ntg * 32 + eu;             // global hidden-unit index
  const size_t pidx = ((size_t)(ku >> 3) * 256 + erow) * 8 + (ku & 7);

  const u16* wbA = wpA + (size_t)(ntg*8 + nw) * (NKA*1024u) + lane*8;
  const u16* wbB = wpB + (size_t)(ntg*8 + nw) * (NKB*1024u) + lane*8;
  const u16* wzA = wzfA + lane*8;
  const u16* wzB = wzfB + lane*8;

  // per-thread recurrent state (row er, unit eu fixed across steps)
  float c1r = 0.f, c2r = 0.f, h2r = 0.f;
  float z1p = 0.f, z2p = 0.f, z1c = 0.f;
  unsigned bar_tgt = 16u;
  int p = 0;

  for (int t = 0; t < TT; ++t) {
    // ======== PHASE A ========
    if (t == 0) {   // no prior prefetch of A1[0]
      for (int j = 0; j < 4; ++j) {
        int i = nw*4 + j; int spl = i >> 4, kq = i & 15;
        const u16* src = A1b[0] + spl*PLSTR + ((size_t)((kq*4 + kgp)*256 + b0 + row16))*8;
        gload_lds16_uc(src, &stgA[0][spl][kq][0][0]);
      }
    }
    for (int j = 0; j < 4; ++j) {     // stage A2 half (fenced by barrier#2 of t-1)
      int i = nw*4 + j; int spl = i >> 4, kq = i & 15;
      const u16* src = A2b + spl*PLSTR + ((size_t)((kq*4 + kgp)*256 + b0 + row16))*8;
      gload_lds16_uc(src, &stgA[1][spl][kq][0][0]);
    }
    for (int j = 0; j < 4; ++j) {     // prefetch B1[p] (fenced by barrier#2 of t-1)
      int i = nw*4 + j; int spl = i >> 4, kq = i & 15;
      const u16* src = B1b[p] + spl*PLSTR + ((size_t)((kq*4 + kgp)*256 + b0 + row16))*8;
      gload_lds16_uc(src, &stgB[0][spl][kq][0][0]);
    }
    // x fragments on the fly (cached f32 reads, static input)
    bf16x8 xah[4], xal[4];
    {
      const float* xp = x + ((size_t)(b0 + row16) * TT + t) * DD + kgp*8;
      for (int k4 = 0; k4 < 4; ++k4) {
        float4 v0 = *(const float4*)(xp + k4*32);
        float4 v1 = *(const float4*)(xp + k4*32 + 4);
        float vv[8] = {v0.x,v0.y,v0.z,v0.w,v1.x,v1.y,v1.z,v1.w};
        for (int e = 0; e < 8; ++e) {
          __bf16 h = (__bf16)vv[e];
          xah[k4][e] = h;
          xal[k4][e] = (__bf16)(vv[e] - (float)h);
        }
      }
    }
    __syncthreads();   // drain staging DMAs + WG barrier

    {
      f32x4 acc0={0,0,0,0}, acc1={0,0,0,0}, acc2={0,0,0,0};
      f32x4 az={0,0,0,0};
      #pragma unroll 4
      for (int kb = 0; kb < 32; ++kb) {
        const u16* sa = &stgA[kb>>4][0][kb&15][lane][0];
        bf16x8 ah = *(const bf16x8*)sa;
        bf16x8 al = *(const bf16x8*)(sa + 8192);
        bf16x8 wh = *(const bf16x8*)(wbA + kb*1024);
        bf16x8 wl = *(const bf16x8*)(wbA + kb*1024 + 512);
        acc0 = __builtin_amdgcn_mfma_f32_16x16x32_bf16(ah, wh, acc0, 0, 0, 0);
        acc1 = __builtin_amdgcn_mfma_f32_16x16x32_bf16(ah, wl, acc1, 0, 0, 0);
        acc2 = __builtin_amdgcn_mfma_f32_16x16x32_bf16(al, wh, acc2, 0, 0, 0);
        if (nw == 0) { bf16x8 zf = *(const bf16x8*)(wzA + kb*512);
                       az = __builtin_amdgcn_mfma_f32_16x16x32_bf16(ah, zf, az, 0, 0, 0); }
        if (nw == 1) { bf16x8 zf = *(const bf16x8*)(wzA + kb*512);
                       az = __builtin_amdgcn_mfma_f32_16x16x32_bf16(al, zf, az, 0, 0, 0); }
      }
      for (int k4 = 0; k4 < 4; ++k4) {
        int kb = 32 + k4;
        bf16x8 ah = xah[k4], al = xal[k4];
        bf16x8 wh = *(const bf16x8*)(wbA + kb*1024);
        bf16x8 wl = *(const bf16x8*)(wbA + kb*1024 + 512);
        acc0 = __builtin_amdgcn_mfma_f32_16x16x32_bf16(ah, wh, acc0, 0, 0, 0);
        acc1 = __builtin_amdgcn_mfma_f32_16x16x32_bf16(ah, wl, acc1, 0, 0, 0);
        acc2 = __builtin_amdgcn_mfma_f32_16x16x32_bf16(al, wh, acc2, 0, 0, 0);
        if (nw == 0) { bf16x8 zf = *(const bf16x8*)(wzA + kb*512);
                       az = __builtin_amdgcn_mfma_f32_16x16x32_bf16(ah, zf, az, 0, 0, 0); }
        if (nw == 1) { bf16x8 zf = *(const bf16x8*)(wzA + kb*512);
                       az = __builtin_amdgcn_mfma_f32_16x16x32_bf16(al, zf, az, 0, 0, 0); }
      }
      f32x4 accs = acc0 + acc1; accs = accs + acc2;
      int cc = nw*16 + (lane & 15);
      int r0 = (lane >> 4) * 4;
      ls_s[r0+0][cc] = accs[0]; ls_s[r0+1][cc] = accs[1];
      ls_s[r0+2][cc] = accs[2]; ls_s[r0+3][cc] = accs[3];
      if (nw == 0 && (lane&15) == 0) {
        for (int j2 = 0; j2 < 4; ++j2) zp[0][r0+j2] = az[j2];
      }
      if (nw == 0 && (lane&15) == 1) {
        for (int j2 = 0; j2 < 4; ++j2) zp[1][r0+j2] = az[j2];
      }
      if (nw == 1 && (lane&15) == 0) {
        for (int j2 = 0; j2 < 4; ++j2) zp[2][r0+j2] = az[j2];
      }
    }
    __syncthreads();
    {
      // epilogue layer 1 (zb==1); znew computed inline per-thread
      float zs = zp[0][er] + zp[1][er] + zp[2][er] + bz1;
      float zn = fminf(fmaxf((zs + 1.f)*0.5f, 0.f), 1.f);
      float4 sv = *(const float4*)&ls_s[er][4*eu];
      float4 bb = *(const float4*)&bp1[ntg*128 + 4*eu];
      float f = sigmoidf_(sv.x + bb.x);
      float i = sigmoidf_(sv.y + bb.y);
      float o = sigmoidf_(sv.z + bb.z);
      float g = tanhf(sv.w + bb.w);
      float z = z1p;
      float ig = i * g;
      float cn = z * ig + (1.f - z) * fmaf(f, c1r, ig);
      float hn = o * tanhf(cn);
      c1r = cn;
      z1c = zn; z1p = zn;
      u16* a1w = A1b[p ^ 1];
      split_st_uc(a1w + pidx, a1w + PLSTR + pidx, (1.f - zn) * hn);   // A next step
      split_st_uc(B2b + pidx, B2b + PLSTR + pidx, zn * hn);           // B this step
    }
    drain_vmem();      // release: all act stores at coherence point
    __syncthreads();   // every wave of this WG drained
    if (tid == 0) {
      __hip_atomic_fetch_add(cnt, 1u, __ATOMIC_RELAXED, __HIP_MEMORY_SCOPE_AGENT);
      while (__hip_atomic_load(cnt, __ATOMIC_RELAXED, __HIP_MEMORY_SCOPE_AGENT) < bar_tgt)
        __builtin_amdgcn_s_sleep(1);
    }
    bar_tgt += 16u;
    __builtin_amdgcn_s_barrier();

    // ======== PHASE B ========
    for (int j = 0; j < 4; ++j) {   // stage B2 (phase-A writes, fenced by barrier#1)
      int i = nw*4 + j; int spl = i >> 4, kq = i & 15;
      const u16* src = B2b + spl*PLSTR + ((size_t)((kq*4 + kgp)*256 + b0 + row16))*8;
      gload_lds16_uc(src, &stgB[1][spl][kq][0][0]);
    }
    for (int j = 0; j < 4; ++j) {   // prefetch A1[p^1] (phase-A writes, fenced by barrier#1)
      int i = nw*4 + j; int spl = i >> 4, kq = i & 15;
      const u16* src = A1b[p ^ 1] + spl*PLSTR + ((size_t)((kq*4 + kgp)*256 + b0 + row16))*8;
      gload_lds16_uc(src, &stgA[0][spl][kq][0][0]);
    }
    __syncthreads();

    {
      f32x4 acc0={0,0,0,0}, acc1={0,0,0,0}, acc2={0,0,0,0};
      f32x4 az={0,0,0,0};
      #pragma unroll 4
      for (int kb = 0; kb < 32; ++kb) {
        const u16* sa = &stgB[kb>>4][0][kb&15][lane][0];
        bf16x8 ah = *(const bf16x8*)sa;
        bf16x8 al = *(const bf16x8*)(sa + 8192);
        bf16x8 wh = *(const bf16x8*)(wbB + kb*1024);
        bf16x8 wl = *(const bf16x8*)(wbB + kb*1024 + 512);
        acc0 = __builtin_amdgcn_mfma_f32_16x16x32_bf16(ah, wh, acc0, 0, 0, 0);
        acc1 = __builtin_amdgcn_mfma_f32_16x16x32_bf16(ah, wl, acc1, 0, 0, 0);
        acc2 = __builtin_amdgcn_mfma_f32_16x16x32_bf16(al, wh, acc2, 0, 0, 0);
        if (nw == 0) { bf16x8 zf = *(const bf16x8*)(wzB + kb*512);
                       az = __builtin_amdgcn_mfma_f32_16x16x32_bf16(ah, zf, az, 0, 0, 0); }
        if (nw == 1) { bf16x8 zf = *(const bf16x8*)(wzB + kb*512);
                       az = __builtin_amdgcn_mfma_f32_16x16x32_bf16(al, zf, az, 0, 0, 0); }
      }
      f32x4 accs = acc0 + acc1; accs = accs + acc2;
      int cc = nw*16 + (lane & 15);
      int r0 = (lane >> 4) * 4;
      ls_s[r0+0][cc] = accs[0]; ls_s[r0+1][cc] = accs[1];
      ls_s[r0+2][cc] = accs[2]; ls_s[r0+3][cc] = accs[3];
      if (nw == 0 && (lane&15) == 0) {
        for (int j2 = 0; j2 < 4; ++j2) zp[0][r0+j2] = az[j2];
      }
      if (nw == 0 && (lane&15) == 1) {
        for (int j2 = 0; j2 < 4; ++j2) zp[1][r0+j2] = az[j2];
      }
      if (nw == 1 && (lane&15) == 0) {
        for (int j2 = 0; j2 < 4; ++j2) zp[2][r0+j2] = az[j2];
      }
    }
    __syncthreads();
    {
      // epilogue layer 2: z = z2(t-1), zb = z1(t); znew inline
      float zs = zp[0][er] + zp[1][er] + zp[2][er] + bz2;
      float z2n_ = fminf(fmaxf((zs + 1.f)*0.5f, 0.f), 1.f);
      float4 sv = *(const float4*)&ls_s[er][4*eu];
      float4 bb = *(const float4*)&bp2[ntg*128 + 4*eu];
      float f = sigmoidf_(sv.x + bb.x);
      float i = sigmoidf_(sv.y + bb.y);
      float o = sigmoidf_(sv.z + bb.z);
      float g = tanhf(sv.w + bb.w);
      float z = z2p, zb = z1c;
      float ig = i * g;
      float cn = z*ig + (1.f-z)*(1.f-zb)*c2r + (1.f-z)*zb*fmaf(f, c2r, ig);
      float tc = tanhf(cn);
      float ot = o * tc;
      float hn = z*ot + (1.f-z)*(1.f-zb)*h2r + (1.f-z)*zb*ot;
      c2r = cn; h2r = hn;
      z2p = z2n_;
      y[((size_t)erow * TT + t) * HH + ku] = hn * z2n_;
      u16* b1w = B1b[p ^ 1];
      split_st_uc(b1w + pidx, b1w + PLSTR + pidx, (1.f - z2n_) * hn);  // B next step
      split_st_uc(A2b + pidx, A2b + PLSTR + pidx, z1c * hn);           // A next step
    }
    drain_vmem();
    __syncthreads();
    if (tid == 0) {
      __hip_atomic_fetch_add(cnt, 1u, __ATOMIC_RELAXED, __HIP_MEMORY_SCOPE_AGENT);
      while (__hip_atomic_load(cnt, __ATOMIC_RELAXED, __HIP_MEMORY_SCOPE_AGENT) < bar_tgt)
        __builtin_amdgcn_s_sleep(1);
    }
    bar_tgt += 16u;
    __builtin_amdgcn_s_barrier();

    p ^= 1;
  }
}

extern "C" void kernel_launch(void* const* d_in, const int* in_sizes, int n_in,
                              void* d_out, int out_size, void* d_ws, size_t ws_size,
                              hipStream_t stream) {
  const float* x     = (const float*)d_in[0];
  const float* U11_1 = (const float*)d_in[1];
  const float* U21_1 = (const float*)d_in[2];
  const float* W01_1 = (const float*)d_in[3];
  const float* b1    = (const float*)d_in[4];
  const float* U11_2 = (const float*)d_in[5];
  const float* W01_2 = (const float*)d_in[6];
  const float* b2    = (const float*)d_in[7];
  char*  wsb = (char*)d_ws;
  float* y   = (float*)d_out;
  (void)in_sizes; (void)n_in; (void)out_size; (void)ws_size;

  u16* wp    = (u16*)(wsb + OFF_WPA);
  u16* wzfa  = (u16*)(wsb + OFF_WZFA);
  u16* wzfb  = (u16*)(wsb + OFF_WZFB);
  float* bp1 = (float*)(wsb + OFF_BP1);
  float* bp2 = (float*)(wsb + OFF_BP2);
  float* bz  = (float*)(wsb + OFF_BZ);

  const unsigned NW = 128u*NKA*2u*512u + 128u*NKB*2u*512u;
  hipLaunchKernelGGL(pack_w, dim3((NW + 255u)/256u), dim3(256), 0, stream,
                     U11_1, U21_1, W01_1, U11_2, W01_2, wp);
  const unsigned NZ = 36u*512u + 32u*512u;
  hipLaunchKernelGGL(pack_wz, dim3((NZ + 255u)/256u), dim3(256), 0, stream,
                     U11_1, U21_1, W01_1, U11_2, W01_2, wzfa, wzfb);
  hipLaunchKernelGGL(pack_bias, dim3(17), dim3(256), 0, stream, b1, b2, bp1, bp2, bz);
  const unsigned n_zero_words = (unsigned)((OFF_END - OFF_CNT) / 4u);
  hipLaunchKernelGGL(init_zero, dim3((n_zero_words + 255u)/256u), dim3(256), 0, stream, wsb);

  const float* xq = x;
  char* wsq = wsb;
  float* yq = y;
  void* kargs[] = { (void*)&xq, (void*)&wsq, (void*)&yq };
  hipLaunchCooperativeKernel((void*)hmlstm_kernel, dim3(256), dim3(512), kargs, 0, stream);
}

// Round 16
// 15538.493 us; speedup vs baseline: 3.0620x; 1.0014x over previous
//
#include <hip/hip_runtime.h>

#define TT 512
#define BB 256
#define DD 128
#define HH 512
#define KA 1152
#define KB 1024
#define NKA 36
#define NKB 32

// ---- ws byte-offset layout ----
#define OFF_WPA  0ull
#define SZ_WPA   (128ull*NKA*2ull*512ull*2ull)     // [colblk][kb][spl][lane][8] bf16
#define OFF_WPB  (OFF_WPA + SZ_WPA)
#define SZ_WPB   (128ull*NKB*2ull*512ull*2ull)
#define OFF_WZFA (OFF_WPB + SZ_WPB)                // [kb][lane][8] u16 (col0=hi,col1=lo)
#define SZ_WZFA  (36ull*512ull*2ull)
#define OFF_WZFB (OFF_WZFA + SZ_WZFA)
#define SZ_WZFB  (32ull*512ull*2ull)
#define OFF_BP1  (OFF_WZFB + SZ_WZFB)              // f32[2048] permuted bias l1
#define OFF_BP2  (OFF_BP1 + 8192ull)
#define OFF_BZ   (OFF_BP2 + 8192ull)               // bz1, bz2
#define OFF_CNT  (OFF_BZ + 256ull)                 // 16 group counters, 256B apart
#define OFF_A1   (OFF_CNT + 4096ull)               // 2 bufs x [2spl][64kg][256row][8] u16
#define OFF_A2   (OFF_A1 + 2ull*524288ull)         // 1 buf
#define OFF_B1   (OFF_A2 + 524288ull)              // 2 bufs
#define OFF_B2   (OFF_B1 + 2ull*524288ull)         // 1 buf
#define OFF_END  (OFF_B2 + 524288ull)

#define PLSTR 131072   // u16 stride between split planes within an act buffer

typedef __bf16 bf16x8 __attribute__((ext_vector_type(8)));
typedef float  f32x4  __attribute__((ext_vector_type(4)));
typedef unsigned short u16;

__device__ __forceinline__ u16 bf_bits(__bf16 h) {
  union { __bf16 b; u16 u; } cv; cv.b = h; return cv.u;
}
__device__ __forceinline__ float sigmoidf_(float v) { return 1.f / (1.f + __expf(-v)); }

// uncached (device-coherent) u16 store: sc0 sc1 -> write-through to coherence point
__device__ __forceinline__ void st_uc(u16* p, u16 v) {
  unsigned vv = v;
  asm volatile("global_store_short %0, %1, off sc0 sc1" :: "v"(p), "v"(vv) : "memory");
}
__device__ __forceinline__ void split_st_uc(u16* hi, u16* lo, float v) {
  __bf16 h = (__bf16)v;
  __bf16 l = (__bf16)(v - (float)h);
  st_uc(hi, bf_bits(h));
  st_uc(lo, bf_bits(l));
}
// explicit drain of ALL outstanding VMEM ops of this wave (inline-asm stores are
// invisible to the compiler's waitcnt scoreboard -- __syncthreads alone is not enough)
__device__ __forceinline__ void drain_vmem() {
  asm volatile("s_waitcnt vmcnt(0)" ::: "memory");
}

// global->LDS DMA, 16B/lane, cpol aux = SC0|NT|SC1 = 19 (device-coherent read; R7-proven)
__device__ __forceinline__ void gload_lds16_uc(const void* g, void* l) {
  __builtin_amdgcn_global_load_lds((const __attribute__((address_space(1))) unsigned int*)g,
                                   (__attribute__((address_space(3))) unsigned int*)l, 16, 0, 19);
}

// ---------------- pack kernels (identical layouts to R5/R7) ----------------
__global__ void pack_w(const float* __restrict__ U11_1, const float* __restrict__ U21_1,
                       const float* __restrict__ W01_1, const float* __restrict__ U11_2,
                       const float* __restrict__ W01_2, u16* __restrict__ wp) {
  unsigned i = blockIdx.x * 256u + threadIdx.x;
  const unsigned NWA = 128u * NKA * 2u * 512u;
  const unsigned NWB = 128u * NKB * 2u * 512u;
  if (i >= NWA + NWB) return;
  float w; unsigned s;
  if (i < NWA) {
    unsigned lane = (i >> 3) & 63u, e = i & 7u; s = (i >> 9) & 1u;
    unsigned blk = i >> 10, kb = blk % NKA, colblk = blk / NKA;
    unsigned c = colblk * 16u + (lane & 15u);
    unsigned n = (c & 3u) * 512u + (c >> 2);
    unsigned k = kb * 32u + (lane >> 4) * 8u + e;
    w = (k < 512u)  ? U11_1[n * 512u + k]
      : (k < 1024u) ? U21_1[n * 512u + (k - 512u)]
                    : W01_1[n * 128u + (k - 1024u)];
  } else {
    unsigned j = i - NWA;
    unsigned lane = (j >> 3) & 63u, e = j & 7u; s = (j >> 9) & 1u;
    unsigned blk = j >> 10, kb = blk % NKB, colblk = blk / NKB;
    unsigned c = colblk * 16u + (lane & 15u);
    unsigned n = (c & 3u) * 512u + (c >> 2);
    unsigned k = kb * 32u + (lane >> 4) * 8u + e;
    w = (k < 512u) ? U11_2[n * 512u + k] : W01_2[n * 512u + (k - 512u)];
  }
  __bf16 hi = (__bf16)w;
  __bf16 v = s ? (__bf16)(w - (float)hi) : hi;
  wp[i] = bf_bits(v);
}

__global__ void pack_wz(const float* __restrict__ U11_1, const float* __restrict__ U21_1,
                        const float* __restrict__ W01_1, const float* __restrict__ U11_2,
                        const float* __restrict__ W01_2,
                        u16* __restrict__ wzfa, u16* __restrict__ wzfb) {
  unsigned i = blockIdx.x * 256u + threadIdx.x;
  const unsigned NZA = 36u * 512u, NZB = 32u * 512u;
  if (i >= NZA + NZB) return;
  const bool isA = i < NZA;
  unsigned j = isA ? i : i - NZA;
  unsigned e = j & 7u, lane = (j >> 3) & 63u, kb = j >> 9;
  unsigned col = lane & 15u;
  unsigned k = kb * 32u + (lane >> 4) * 8u + e;
  float wz;
  if (isA) {
    wz = (k < 512u)  ? U11_1[2048u*512u + k]
       : (k < 1024u) ? U21_1[2048u*512u + (k-512u)]
                     : W01_1[2048u*128u + (k-1024u)];
  } else {
    wz = (k < 512u) ? U11_2[2048u*512u + k] : W01_2[2048u*512u + (k-512u)];
  }
  u16 out = 0;
  if (col == 0u) out = bf_bits((__bf16)wz);
  else if (col == 1u) { __bf16 h = (__bf16)wz; out = bf_bits((__bf16)(wz - (float)h)); }
  (isA ? wzfa : wzfb)[j] = out;
}

__global__ void pack_bias(const float* __restrict__ b1, const float* __restrict__ b2,
                          float* __restrict__ bp1, float* __restrict__ bp2,
                          float* __restrict__ bz) {
  unsigned i = blockIdx.x * 256u + threadIdx.x;
  if (i < 2048u) bp1[i] = b1[(i & 3u)*512u + (i >> 2)];
  else if (i < 4096u) { unsigned c = i - 2048u; bp2[c] = b2[(c & 3u)*512u + (c >> 2)]; }
  else if (i == 4096u) bz[0] = b1[2048];
  else if (i == 4097u) bz[1] = b2[2048];
}

// zero act buffers + counters
__global__ void init_zero(char* __restrict__ wsb) {
  size_t i = (size_t)blockIdx.x * 256u + threadIdx.x;
  size_t n = (OFF_END - OFF_CNT) / 4u;
  if (i < n) ((unsigned*)(wsb + OFF_CNT))[i] = 0u;
}

// ---------------- main persistent kernel (exact R7 revert, 15.6 ms proven) ----------------
// 256 WGs x 512 threads. WG = 16 rows (mg) x 128 cols (ntg).
// XCD x (bid&7) hosts ntg {2x,2x+1} for all 16 mgs -> 2.2 MB L2-resident weights.
// Cross-WG deps exist ONLY within an mg-group (16 WGs sharing rows) -> 16
// independent group barriers (one counter per mg, own cache line). No L2
// invalidation anywhere; acts via device-coherent stores + coherent DMA reads.
// All inline-asm stores are explicitly drained (vmcnt0) before barrier arrival.
__global__ __launch_bounds__(512, 2) void hmlstm_kernel(const float* __restrict__ x,
                                                        char* __restrict__ wsb,
                                                        float* __restrict__ y) {
  const int tid  = threadIdx.x;
  const int lane = tid & 63;
  const int nw   = __builtin_amdgcn_readfirstlane(tid >> 6);
  const int bid  = blockIdx.x;
  const int ntg  = (bid & 7) * 2 + (bid >> 7);   // 0..15
  const int mg   = (bid >> 3) & 15;              // 0..15
  const int b0   = mg * 16;

  const u16* wpA  = (const u16*)(wsb + OFF_WPA);
  const u16* wpB  = (const u16*)(wsb + OFF_WPB);
  const u16* wzfA = (const u16*)(wsb + OFF_WZFA);
  const u16* wzfB = (const u16*)(wsb + OFF_WZFB);
  const float* bp1 = (const float*)(wsb + OFF_BP1);
  const float* bp2 = (const float*)(wsb + OFF_BP2);
  const float bz1 = ((const float*)(wsb + OFF_BZ))[0];
  const float bz2 = ((const float*)(wsb + OFF_BZ))[1];
  unsigned* cnt = (unsigned*)(wsb + OFF_CNT) + mg * 64;   // own 256B line
  u16* A1b[2] = { (u16*)(wsb + OFF_A1), (u16*)(wsb + OFF_A1 + 524288ull) };
  u16* A2b    =   (u16*)(wsb + OFF_A2);
  u16* B1b[2] = { (u16*)(wsb + OFF_B1), (u16*)(wsb + OFF_B1 + 524288ull) };
  u16* B2b    =   (u16*)(wsb + OFF_B2);

  __shared__ u16 stgA[2][2][16][64][8];   // 64 KB
  __shared__ u16 stgB[2][2][16][64][8];   // 64 KB
  __shared__ float ls_s[16][132];
  __shared__ float zp[3][16];

  const int kgp   = lane >> 4;    // k-slot 0..3
  const int row16 = lane & 15;    // frag row 0..15
  const int er = tid >> 5, eu = tid & 31;   // epilogue (row, unit-in-WG)
  const int erow = b0 + er;
  const int ku = ntg * 32 + eu;             // global hidden-unit index
  const size_t pidx = ((size_t)(ku >> 3) * 256 + erow) * 8 + (ku & 7);

  const u16* wbA = wpA + (size_t)(ntg*8 + nw) * (NKA*1024u) + lane*8;
  const u16* wbB = wpB + (size_t)(ntg*8 + nw) * (NKB*1024u) + lane*8;
  const u16* wzA = wzfA + lane*8;
  const u16* wzB = wzfB + lane*8;

  // per-thread recurrent state (row er, unit eu fixed across steps)
  float c1r = 0.f, c2r = 0.f, h2r = 0.f;
  float z1p = 0.f, z2p = 0.f, z1c = 0.f;
  unsigned bar_tgt = 16u;
  int p = 0;

  for (int t = 0; t < TT; ++t) {
    // ======== PHASE A ========
    if (t == 0) {   // no prior prefetch of A1[0]
      for (int j = 0; j < 4; ++j) {
        int i = nw*4 + j; int spl = i >> 4, kq = i & 15;
        const u16* src = A1b[0] + spl*PLSTR + ((size_t)((kq*4 + kgp)*256 + b0 + row16))*8;
        gload_lds16_uc(src, &stgA[0][spl][kq][0][0]);
      }
    }
    for (int j = 0; j < 4; ++j) {     // stage A2 half (fenced by barrier#2 of t-1)
      int i = nw*4 + j; int spl = i >> 4, kq = i & 15;
      const u16* src = A2b + spl*PLSTR + ((size_t)((kq*4 + kgp)*256 + b0 + row16))*8;
      gload_lds16_uc(src, &stgA[1][spl][kq][0][0]);
    }
    for (int j = 0; j < 4; ++j) {     // prefetch B1[p] (fenced by barrier#2 of t-1)
      int i = nw*4 + j; int spl = i >> 4, kq = i & 15;
      const u16* src = B1b[p] + spl*PLSTR + ((size_t)((kq*4 + kgp)*256 + b0 + row16))*8;
      gload_lds16_uc(src, &stgB[0][spl][kq][0][0]);
    }
    // x fragments on the fly (cached f32 reads, static input)
    bf16x8 xah[4], xal[4];
    {
      const float* xp = x + ((size_t)(b0 + row16) * TT + t) * DD + kgp*8;
      for (int k4 = 0; k4 < 4; ++k4) {
        float4 v0 = *(const float4*)(xp + k4*32);
        float4 v1 = *(const float4*)(xp + k4*32 + 4);
        float vv[8] = {v0.x,v0.y,v0.z,v0.w,v1.x,v1.y,v1.z,v1.w};
        for (int e = 0; e < 8; ++e) {
          __bf16 h = (__bf16)vv[e];
          xah[k4][e] = h;
          xal[k4][e] = (__bf16)(vv[e] - (float)h);
        }
      }
    }
    __syncthreads();   // drain staging DMAs + WG barrier

    {
      f32x4 acc0={0,0,0,0}, acc1={0,0,0,0}, acc2={0,0,0,0};
      f32x4 az={0,0,0,0};
      #pragma unroll 4
      for (int kb = 0; kb < 32; ++kb) {
        const u16* sa = &stgA[kb>>4][0][kb&15][lane][0];
        bf16x8 ah = *(const bf16x8*)sa;
        bf16x8 al = *(const bf16x8*)(sa + 8192);
        bf16x8 wh = *(const bf16x8*)(wbA + kb*1024);
        bf16x8 wl = *(const bf16x8*)(wbA + kb*1024 + 512);
        acc0 = __builtin_amdgcn_mfma_f32_16x16x32_bf16(ah, wh, acc0, 0, 0, 0);
        acc1 = __builtin_amdgcn_mfma_f32_16x16x32_bf16(ah, wl, acc1, 0, 0, 0);
        acc2 = __builtin_amdgcn_mfma_f32_16x16x32_bf16(al, wh, acc2, 0, 0, 0);
        if (nw == 0) { bf16x8 zf = *(const bf16x8*)(wzA + kb*512);
                       az = __builtin_amdgcn_mfma_f32_16x16x32_bf16(ah, zf, az, 0, 0, 0); }
        if (nw == 1) { bf16x8 zf = *(const bf16x8*)(wzA + kb*512);
                       az = __builtin_amdgcn_mfma_f32_16x16x32_bf16(al, zf, az, 0, 0, 0); }
      }
      for (int k4 = 0; k4 < 4; ++k4) {
        int kb = 32 + k4;
        bf16x8 ah = xah[k4], al = xal[k4];
        bf16x8 wh = *(const bf16x8*)(wbA + kb*1024);
        bf16x8 wl = *(const bf16x8*)(wbA + kb*1024 + 512);
        acc0 = __builtin_amdgcn_mfma_f32_16x16x32_bf16(ah, wh, acc0, 0, 0, 0);
        acc1 = __builtin_amdgcn_mfma_f32_16x16x32_bf16(ah, wl, acc1, 0, 0, 0);
        acc2 = __builtin_amdgcn_mfma_f32_16x16x32_bf16(al, wh, acc2, 0, 0, 0);
        if (nw == 0) { bf16x8 zf = *(const bf16x8*)(wzA + kb*512);
                       az = __builtin_amdgcn_mfma_f32_16x16x32_bf16(ah, zf, az, 0, 0, 0); }
        if (nw == 1) { bf16x8 zf = *(const bf16x8*)(wzA + kb*512);
                       az = __builtin_amdgcn_mfma_f32_16x16x32_bf16(al, zf, az, 0, 0, 0); }
      }
      f32x4 accs = acc0 + acc1; accs = accs + acc2;
      int cc = nw*16 + (lane & 15);
      int r0 = (lane >> 4) * 4;
      ls_s[r0+0][cc] = accs[0]; ls_s[r0+1][cc] = accs[1];
      ls_s[r0+2][cc] = accs[2]; ls_s[r0+3][cc] = accs[3];
      if (nw == 0 && (lane&15) == 0) {
        for (int j2 = 0; j2 < 4; ++j2) zp[0][r0+j2] = az[j2];
      }
      if (nw == 0 && (lane&15) == 1) {
        for (int j2 = 0; j2 < 4; ++j2) zp[1][r0+j2] = az[j2];
      }
      if (nw == 1 && (lane&15) == 0) {
        for (int j2 = 0; j2 < 4; ++j2) zp[2][r0+j2] = az[j2];
      }
    }
    __syncthreads();
    {
      // epilogue layer 1 (zb==1); znew computed inline per-thread
      float zs = zp[0][er] + zp[1][er] + zp[2][er] + bz1;
      float zn = fminf(fmaxf((zs + 1.f)*0.5f, 0.f), 1.f);
      float4 sv = *(const float4*)&ls_s[er][4*eu];
      float4 bb = *(const float4*)&bp1[ntg*128 + 4*eu];
      float f = sigmoidf_(sv.x + bb.x);
      float i = sigmoidf_(sv.y + bb.y);
      float o = sigmoidf_(sv.z + bb.z);
      float g = tanhf(sv.w + bb.w);
      float z = z1p;
      float ig = i * g;
      float cn = z * ig + (1.f - z) * fmaf(f, c1r, ig);
      float hn = o * tanhf(cn);
      c1r = cn;
      z1c = zn; z1p = zn;
      u16* a1w = A1b[p ^ 1];
      split_st_uc(a1w + pidx, a1w + PLSTR + pidx, (1.f - zn) * hn);   // A next step
      split_st_uc(B2b + pidx, B2b + PLSTR + pidx, zn * hn);           // B this step
    }
    drain_vmem();      // release: all act stores at coherence point
    __syncthreads();   // every wave of this WG drained
    if (tid == 0) {
      __hip_atomic_fetch_add(cnt, 1u, __ATOMIC_RELAXED, __HIP_MEMORY_SCOPE_AGENT);
      while (__hip_atomic_load(cnt, __ATOMIC_RELAXED, __HIP_MEMORY_SCOPE_AGENT) < bar_tgt)
        __builtin_amdgcn_s_sleep(1);
    }
    bar_tgt += 16u;
    __builtin_amdgcn_s_barrier();

    // ======== PHASE B ========
    for (int j = 0; j < 4; ++j) {   // stage B2 (phase-A writes, fenced by barrier#1)
      int i = nw*4 + j; int spl = i >> 4, kq = i & 15;
      const u16* src = B2b + spl*PLSTR + ((size_t)((kq*4 + kgp)*256 + b0 + row16))*8;
      gload_lds16_uc(src, &stgB[1][spl][kq][0][0]);
    }
    for (int j = 0; j < 4; ++j) {   // prefetch A1[p^1] (phase-A writes, fenced by barrier#1)
      int i = nw*4 + j; int spl = i >> 4, kq = i & 15;
      const u16* src = A1b[p ^ 1] + spl*PLSTR + ((size_t)((kq*4 + kgp)*256 + b0 + row16))*8;
      gload_lds16_uc(src, &stgA[0][spl][kq][0][0]);
    }
    __syncthreads();

    {
      f32x4 acc0={0,0,0,0}, acc1={0,0,0,0}, acc2={0,0,0,0};
      f32x4 az={0,0,0,0};
      #pragma unroll 4
      for (int kb = 0; kb < 32; ++kb) {
        const u16* sa = &stgB[kb>>4][0][kb&15][lane][0];
        bf16x8 ah = *(const bf16x8*)sa;
        bf16x8 al = *(const bf16x8*)(sa + 8192);
        bf16x8 wh = *(const bf16x8*)(wbB + kb*1024);
        bf16x8 wl = *(const bf16x8*)(wbB + kb*1024 + 512);
        acc0 = __builtin_amdgcn_mfma_f32_16x16x32_bf16(ah, wh, acc0, 0, 0, 0);
        acc1 = __builtin_amdgcn_mfma_f32_16x16x32_bf16(ah, wl, acc1, 0, 0, 0);
        acc2 = __builtin_amdgcn_mfma_f32_16x16x32_bf16(al, wh, acc2, 0, 0, 0);
        if (nw == 0) { bf16x8 zf = *(const bf16x8*)(wzB + kb*512);
                       az = __builtin_amdgcn_mfma_f32_16x16x32_bf16(ah, zf, az, 0, 0, 0); }
        if (nw == 1) { bf16x8 zf = *(const bf16x8*)(wzB + kb*512);
                       az = __builtin_amdgcn_mfma_f32_16x16x32_bf16(al, zf, az, 0, 0, 0); }
      }
      f32x4 accs = acc0 + acc1; accs = accs + acc2;
      int cc = nw*16 + (lane & 15);
      int r0 = (lane >> 4) * 4;
      ls_s[r0+0][cc] = accs[0]; ls_s[r0+1][cc] = accs[1];
      ls_s[r0+2][cc] = accs[2]; ls_s[r0+3][cc] = accs[3];
      if (nw == 0 && (lane&15) == 0) {
        for (int j2 = 0; j2 < 4; ++j2) zp[0][r0+j2] = az[j2];
      }
      if (nw == 0 && (lane&15) == 1) {
        for (int j2 = 0; j2 < 4; ++j2) zp[1][r0+j2] = az[j2];
      }
      if (nw == 1 && (lane&15) == 0) {
        for (int j2 = 0; j2 < 4; ++j2) zp[2][r0+j2] = az[j2];
      }
    }
    __syncthreads();
    {
      // epilogue layer 2: z = z2(t-1), zb = z1(t); znew inline
      float zs = zp[0][er] + zp[1][er] + zp[2][er] + bz2;
      float z2n_ = fminf(fmaxf((zs + 1.f)*0.5f, 0.f), 1.f);
      float4 sv = *(const float4*)&ls_s[er][4*eu];
      float4 bb = *(const float4*)&bp2[ntg*128 + 4*eu];
      float f = sigmoidf_(sv.x + bb.x);
      float i = sigmoidf_(sv.y + bb.y);
      float o = sigmoidf_(sv.z + bb.z);
      float g = tanhf(sv.w + bb.w);
      float z = z2p, zb = z1c;
      float ig = i * g;
      float cn = z*ig + (1.f-z)*(1.f-zb)*c2r + (1.f-z)*zb*fmaf(f, c2r, ig);
      float tc = tanhf(cn);
      float ot = o * tc;
      float hn = z*ot + (1.f-z)*(1.f-zb)*h2r + (1.f-z)*zb*ot;
      c2r = cn; h2r = hn;
      z2p = z2n_;
      y[((size_t)erow * TT + t) * HH + ku] = hn * z2n_;
      u16* b1w = B1b[p ^ 1];
      split_st_uc(b1w + pidx, b1w + PLSTR + pidx, (1.f - z2n_) * hn);  // B next step
      split_st_uc(A2b + pidx, A2b + PLSTR + pidx, z1c * hn);           // A next step
    }
    drain_vmem();
    __syncthreads();
    if (tid == 0) {
      __hip_atomic_fetch_add(cnt, 1u, __ATOMIC_RELAXED, __HIP_MEMORY_SCOPE_AGENT);
      while (__hip_atomic_load(cnt, __ATOMIC_RELAXED, __HIP_MEMORY_SCOPE_AGENT) < bar_tgt)
        __builtin_amdgcn_s_sleep(1);
    }
    bar_tgt += 16u;
    __builtin_amdgcn_s_barrier();

    p ^= 1;
  }
}

extern "C" void kernel_launch(void* const* d_in, const int* in_sizes, int n_in,
                              void* d_out, int out_size, void* d_ws, size_t ws_size,
                              hipStream_t stream) {
  const float* x     = (const float*)d_in[0];
  const float* U11_1 = (const float*)d_in[1];
  const float* U21_1 = (const float*)d_in[2];
  const float* W01_1 = (const float*)d_in[3];
  const float* b1    = (const float*)d_in[4];
  const float* U11_2 = (const float*)d_in[5];
  const float* W01_2 = (const float*)d_in[6];
  const float* b2    = (const float*)d_in[7];
  char*  wsb = (char*)d_ws;
  float* y   = (float*)d_out;
  (void)in_sizes; (void)n_in; (void)out_size; (void)ws_size;

  u16* wp    = (u16*)(wsb + OFF_WPA);
  u16* wzfa  = (u16*)(wsb + OFF_WZFA);
  u16* wzfb  = (u16*)(wsb + OFF_WZFB);
  float* bp1 = (float*)(wsb + OFF_BP1);
  float* bp2 = (float*)(wsb + OFF_BP2);
  float* bz  = (float*)(wsb + OFF_BZ);

  const unsigned NW = 128u*NKA*2u*512u + 128u*NKB*2u*512u;
  hipLaunchKernelGGL(pack_w, dim3((NW + 255u)/256u), dim3(256), 0, stream,
                     U11_1, U21_1, W01_1, U11_2, W01_2, wp);
  const unsigned NZ = 36u*512u + 32u*512u;
  hipLaunchKernelGGL(pack_wz, dim3((NZ + 255u)/256u), dim3(256), 0, stream,
                     U11_1, U21_1, W01_1, U11_2, W01_2, wzfa, wzfb);
  hipLaunchKernelGGL(pack_bias, dim3(17), dim3(256), 0, stream, b1, b2, bp1, bp2, bz);
  const unsigned n_zero_words = (unsigned)((OFF_END - OFF_CNT) / 4u);
  hipLaunchKernelGGL(init_zero, dim3((n_zero_words + 255u)/256u), dim3(256), 0, stream, wsb);

  const float* xq = x;
  char* wsq = wsb;
  float* yq = y;
  void* kargs[] = { (void*)&xq, (void*)&wsq, (void*)&yq };
  hipLaunchCooperativeKernel((void*)hmlstm_kernel, dim3(256), dim3(512), kargs, 0, stream);
}